// Round 9
// baseline (1632.998 us; speedup 1.0000x reference)
//
#include <hip/hip_runtime.h>
#include <hip/hip_bf16.h>

#define NN 50000
#define NE 800000
#define NB 16
#define T_STEPS 12
#define SCAN_B 196  // ceil(NN/256)

typedef __attribute__((ext_vector_type(8))) short short8;
typedef __attribute__((ext_vector_type(4))) float f32x4;
typedef __attribute__((ext_vector_type(2))) float f32x2;
typedef unsigned short u16;
typedef unsigned int u32;

__device__ __forceinline__ float bf2f(u32 u) {
    union { u32 i; float f; } v; v.i = u << 16; return v.f;
}
__device__ __forceinline__ u16 f2bf(float f) {
    union { float f; u32 i; } v; v.f = f;
    u32 r = v.i + 0x7fffu + ((v.i >> 16) & 1u);
    return (u16)(r >> 16);
}
__device__ __forceinline__ f32x4 mfma16(short8 a, short8 b, f32x4 c) {
    return __builtin_amdgcn_mfma_f32_16x16x32_bf16(a, b, c, 0, 0, 0);
}

// pack 2 floats -> fp8 e4m3 pair in low 16 bits (HW instruction; OCP on gfx950)
__device__ __forceinline__ u32 pk2_fp8(float o0, float o1) {
#if __has_builtin(__builtin_amdgcn_cvt_pk_fp8_f32)
    return (u32)__builtin_amdgcn_cvt_pk_fp8_f32(o0, o1, 0, false);
#else
    u32 a = 0;
    asm("v_cvt_pk_fp8_f32 %0, %1, %2" : "+v"(a) : "v"(o0), "v"(o1));
    return a;
#endif
}
__device__ __forceinline__ u32 pk4_fp8(float o0, float o1, float o2, float o3) {
    return (pk2_fp8(o0, o1) & 0xffffu) | (pk2_fp8(o2, o3) << 16);
}

// decode 4x fp8 e4m3 from u32
__device__ __forceinline__ void fp8x4f(u32 w, float& f0, float& f1, float& f2, float& f3) {
#if __has_builtin(__builtin_amdgcn_cvt_pk_f32_fp8)
    f32x2 r0 = __builtin_amdgcn_cvt_pk_f32_fp8((int)w, false);
    f32x2 r1 = __builtin_amdgcn_cvt_pk_f32_fp8((int)w, true);
    f0 = r0[0]; f1 = r0[1]; f2 = r1[0]; f3 = r1[1];
#else
    f32x2 r0, r1;
    u32 hi = w >> 16;
    asm("v_cvt_pk_f32_fp8 %0, %1" : "=v"(r0) : "v"(w));
    asm("v_cvt_pk_f32_fp8 %0, %1" : "=v"(r1) : "v"(hi));
    f0 = r0[0]; f1 = r0[1]; f2 = r1[0]; f3 = r1[1];
#endif
}

// packed weight layout (bf16): elem(((ks*8+nt)*64+l)*8+j) = W[ks*32+((l>>4))*8+j][nt*16+(l&15)]
#define W1OFF 0
#define W2OFF 32768
#define WSOFF 49152
#define ENCOFF 65536
#define PACKN 73728

// ---------------- setup kernels ----------------

__global__ void k_hist(const int* __restrict__ dst, int* __restrict__ hist) {
    int e = blockIdx.x * 256 + threadIdx.x;
    if (e < NE) atomicAdd(&hist[dst[e]], 1);
}

__global__ void k_scanA(const int* __restrict__ hist, int* __restrict__ excl,
                        int* __restrict__ bsum) {
    __shared__ int sh[256];
    int t = threadIdx.x, b = blockIdx.x;
    int idx = b * 256 + t;
    int v = (idx < NN) ? hist[idx] : 0;
    sh[t] = v;
    __syncthreads();
    for (int off = 1; off < 256; off <<= 1) {
        int add = (t >= off) ? sh[t - off] : 0;
        __syncthreads();
        sh[t] += add;
        __syncthreads();
    }
    if (idx < NN) excl[idx] = sh[t] - v;
    if (t == 255) bsum[b] = sh[255];
}

__global__ void k_scanB(int* __restrict__ bsum) {
    __shared__ int sh[256];
    int t = threadIdx.x;
    int v = (t < SCAN_B) ? bsum[t] : 0;
    sh[t] = v;
    __syncthreads();
    for (int off = 1; off < 256; off <<= 1) {
        int add = (t >= off) ? sh[t - off] : 0;
        __syncthreads();
        sh[t] += add;
        __syncthreads();
    }
    if (t < SCAN_B) bsum[t] = sh[t] - v;  // exclusive
}

__global__ void k_scanC(const int* __restrict__ excl, const int* __restrict__ bsum,
                        int* __restrict__ rowptr, int* __restrict__ cursor) {
    int idx = blockIdx.x * 256 + threadIdx.x;
    if (idx < NN) {
        int r = excl[idx] + bsum[blockIdx.x];
        rowptr[idx] = r;
        cursor[idx] = r;
    }
    if (idx == 0) rowptr[NN] = NE;
}

// scatter (src, edge-id) as one int2 per edge
__global__ void k_scatter(const int* __restrict__ src, const int* __restrict__ dst,
                          int* __restrict__ cursor, int2* __restrict__ sse) {
    int e = blockIdx.x * 256 + threadIdx.x;
    if (e >= NE) return;
    int d = dst[e];
    int pos = atomicAdd(&cursor[d], 1);
    int2 v; v.x = src[e]; v.y = e;
    sse[pos] = v;
}

// eaw[p][c] = fp8( sum_k eattr[sse[p].y][k] * msg_w[128+k][c] )  (CSR position p)
// one 256-edge tile per block; eattr staged in LDS; weights in VGPRs (w[8][8]).
__global__ __launch_bounds__(256) void k_eaw(
    const int2* __restrict__ sse, const float* __restrict__ eattr,
    const float* __restrict__ msg_w, unsigned char* __restrict__ eaw) {
    __shared__ float elds[256][8];
    const int tid = threadIdx.x;
    const int hex = tid & 15;   // channel slice [hex*8, hex*8+8)
    const int esub = tid >> 4;  // 0..15
    float w[8][8];
#pragma unroll
    for (int k = 0; k < 8; ++k) {
        float4 v0 = *(const float4*)(msg_w + (size_t)(128 + k) * 128 + hex * 8);
        float4 v1 = *(const float4*)(msg_w + (size_t)(128 + k) * 128 + hex * 8 + 4);
        w[k][0] = v0.x; w[k][1] = v0.y; w[k][2] = v0.z; w[k][3] = v0.w;
        w[k][4] = v1.x; w[k][5] = v1.y; w[k][6] = v1.z; w[k][7] = v1.w;
    }
    const int p0 = blockIdx.x * 256;
    {
        int eid = sse[p0 + tid].y;
        const float* ar = eattr + (size_t)eid * 8;
        float4 a0 = *(const float4*)ar;
        float4 a1 = *(const float4*)(ar + 4);
        *(float4*)&elds[tid][0] = a0;
        *(float4*)&elds[tid][4] = a1;
    }
    __syncthreads();
#pragma unroll 4
    for (int j = 0; j < 16; ++j) {
        int idx = esub + j * 16;
        float4 a0 = *(const float4*)&elds[idx][0];
        float4 a1 = *(const float4*)&elds[idx][4];
        float ef[8] = {a0.x, a0.y, a0.z, a0.w, a1.x, a1.y, a1.z, a1.w};
        float o[8];
#pragma unroll
        for (int c = 0; c < 8; ++c) o[c] = ef[0] * w[0][c];
#pragma unroll
        for (int k = 1; k < 8; ++k)
#pragma unroll
            for (int c = 0; c < 8; ++c) o[c] += ef[k] * w[k][c];
        uint2 q;
        q.x = pk4_fp8(o[0], o[1], o[2], o[3]);
        q.y = pk4_fp8(o[4], o[5], o[6], o[7]);
        *(uint2*)(eaw + (size_t)(p0 + idx) * 128 + hex * 8) = q;
    }
}

__global__ void k_pack(const float* __restrict__ up_w1, const float* __restrict__ up_w2,
                       const float* __restrict__ msg_w, const float* __restrict__ enc_w,
                       u16* __restrict__ packed) {
    int idx = blockIdx.x * 256 + threadIdx.x;
    if (idx >= PACKN) return;
    const float* srcp; int local;
    if (idx < W2OFF)        { srcp = up_w1; local = idx; }
    else if (idx < WSOFF)   { srcp = up_w2; local = idx - W2OFF; }
    else if (idx < ENCOFF)  { srcp = msg_w; local = idx - WSOFF; }   // rows 0..127 (state part)
    else                    { srcp = enc_w; local = idx - ENCOFF; }
    int j = local & 7;
    int l = (local >> 3) & 63;
    int ntks = local >> 9;
    int nt = ntks & 7;
    int ks = ntks >> 3;
    int krow = ks * 32 + (l >> 4) * 8 + j;
    int col = nt * 16 + (l & 15);
    packed[idx] = f2bf(srcp[krow * 128 + col]);
}

// ---------------- encoder: state = relu(x@enc_w+enc_b); SW = state@Ws + msg_b ----------------

__global__ __launch_bounds__(256) void k_encode(
    const float* __restrict__ x, const float* __restrict__ enc_b,
    const float* __restrict__ msg_b, const u16* __restrict__ packed,
    float* __restrict__ state_f, u16* __restrict__ state_h, u16* __restrict__ swb) {
    __shared__ u16 stage[4][2048];
    const int wv = threadIdx.x >> 6, l = threadIdx.x & 63;
    const int lr = l & 15, kb = l >> 4;
    const int rb = blockIdx.x * 64 + wv * 16;
    const int row = rb + lr;
    const int rowc = row < NN ? row : NN - 1;

    f32x4 acc[8] = {};
#pragma unroll
    for (int ks = 0; ks < 2; ++ks) {
        const float* ap = x + (size_t)rowc * 64 + ks * 32 + kb * 8;
        float4 a0 = *(const float4*)ap;
        float4 a1 = *(const float4*)(ap + 4);
        short8 a;
        a[0] = (short)f2bf(a0.x); a[1] = (short)f2bf(a0.y);
        a[2] = (short)f2bf(a0.z); a[3] = (short)f2bf(a0.w);
        a[4] = (short)f2bf(a1.x); a[5] = (short)f2bf(a1.y);
        a[6] = (short)f2bf(a1.z); a[7] = (short)f2bf(a1.w);
        const u16* bp = packed + ENCOFF + (size_t)(ks * 512 + l) * 8;
#pragma unroll
        for (int nt = 0; nt < 8; ++nt) {
            short8 b = *(const short8*)(bp + nt * 512);
            acc[nt] = mfma16(a, b, acc[nt]);
        }
    }
#pragma unroll
    for (int nt = 0; nt < 8; ++nt) {
        int col = nt * 16 + lr;
        float bias = enc_b[col];
#pragma unroll
        for (int j = 0; j < 4; ++j) {
            int rl = kb * 4 + j;
            int r = rb + rl;
            float v = acc[nt][j] + bias;
            v = v > 0.f ? v : 0.f;
            u16 h = f2bf(v);
            if (r < NN) {
                state_f[(size_t)r * 128 + col] = v;
                state_h[(size_t)r * 128 + col] = h;
            }
            int byte = (rl * 256 + col * 2) ^ ((rl & 7) << 4);
            *(u16*)((char*)stage[wv] + byte) = h;
        }
    }
    f32x4 acc3[8] = {};
#pragma unroll
    for (int ks = 0; ks < 4; ++ks) {
        int byte = (lr * 256 + ks * 64 + kb * 16) ^ ((lr & 7) << 4);
        short8 a = *(const short8*)((char*)stage[wv] + byte);
        const u16* bp = packed + WSOFF + (size_t)(ks * 512 + l) * 8;
#pragma unroll
        for (int nt = 0; nt < 8; ++nt) {
            short8 b = *(const short8*)(bp + nt * 512);
            acc3[nt] = mfma16(a, b, acc3[nt]);
        }
    }
#pragma unroll
    for (int nt = 0; nt < 8; ++nt) {
        int col = nt * 16 + lr;
        float bias = msg_b[col];
#pragma unroll
        for (int j = 0; j < 4; ++j) {
            int r = rb + kb * 4 + j;
            if (r < NN) swb[(size_t)r * 128 + col] = f2bf(acc3[nt][j] + bias);
        }
    }
}

// ---------------- fused step kernel ----------------
// Per wave: 16 rows. Phase A: agg for those rows from swb_in (gather) -> wave-local LDS
// (XOR-swizzled stage format). Phase B: h=relu([state,agg]@W1+b1); state+=h@W2+b2;
// swb_out = state@Ws+msg_b. swb ping-pong across dispatches; zero __syncthreads.

#define STEP_SMEM_PER_WAVE 8224  // 4096 aggl + 4128 union(red[8][129] f32 / stage 4096)

__global__ __launch_bounds__(256) void k_step(
    const int* __restrict__ rowptr, const int2* __restrict__ sse,
    const unsigned char* __restrict__ eaw, const u16* __restrict__ swb_in,
    const float* __restrict__ up_b1, const float* __restrict__ up_b2,
    const float* __restrict__ msg_b, const u16* __restrict__ packed,
    float* __restrict__ state_f, u16* __restrict__ state_h,
    u16* __restrict__ swb_out) {
    __shared__ char smem[4 * STEP_SMEM_PER_WAVE];
    const int wv = threadIdx.x >> 6, l = threadIdx.x & 63;
    char* wbase = smem + wv * STEP_SMEM_PER_WAVE;
    u16* aggl = (u16*)wbase;                   // 16x128 bf16, stage format
    float* red = (float*)(wbase + 4096);       // [8][129]
    u16* stage = (u16*)(wbase + 4096);         // phase-B h / state staging (reuses red area)
    const int rbase = blockIdx.x * 64 + wv * 16;

    // ---- Phase A: aggregate edges for rows rbase..rbase+15 ----
    {
        const int slot = l >> 3, g = l & 7;
        for (int nl = 0; nl < 16; ++nl) {
            int n = rbase + nl;
            int nc = n < NN ? n : NN - 1;
            int e0 = rowptr[nc], e1 = rowptr[nc + 1];
            float acc[16];
#pragma unroll
            for (int c = 0; c < 16; ++c) acc[c] = 0.f;
            int i = e0 + slot;
            int s = (i < e1) ? sse[i].x : 0;
            while (i < e1) {
                int inext = i + 8;
                int snext = (inext < e1) ? sse[inext].x : 0;
                uint4 q = *(const uint4*)(eaw + (size_t)i * 128 + g * 16);
                const u16* sp = swb_in + (size_t)s * 128 + g * 16;
                uint4 sa = *(const uint4*)sp;
                uint4 sb = *(const uint4*)(sp + 8);
                float ef[16];
                fp8x4f(q.x, ef[0], ef[1], ef[2], ef[3]);
                fp8x4f(q.y, ef[4], ef[5], ef[6], ef[7]);
                fp8x4f(q.z, ef[8], ef[9], ef[10], ef[11]);
                fp8x4f(q.w, ef[12], ef[13], ef[14], ef[15]);
                u32 sw[8] = {sa.x, sa.y, sa.z, sa.w, sb.x, sb.y, sb.z, sb.w};
#pragma unroll
                for (int h = 0; h < 8; ++h) {
                    union { u32 i; float f; } vlo, vhi;
                    vlo.i = sw[h] << 16;
                    vhi.i = sw[h] & 0xffff0000u;
                    float m0 = vlo.f + ef[2 * h];
                    float m1 = vhi.f + ef[2 * h + 1];
                    acc[2 * h]     += m0 > 0.f ? m0 : 0.f;
                    acc[2 * h + 1] += m1 > 0.f ? m1 : 0.f;
                }
                i = inext;
                s = snext;
            }
            // slot reduction (wave-local LDS, R8-proven layout)
            float* rp = red + slot * 129 + g * 16;
#pragma unroll
            for (int c = 0; c < 16; c += 4) {
                f32x4 v = {acc[c], acc[c + 1], acc[c + 2], acc[c + 3]};
                *(f32x4*)(rp + c) = v;
            }
            float v0 = 0.f, v1 = 0.f;
#pragma unroll
            for (int sl = 0; sl < 8; ++sl) {
                v0 += red[sl * 129 + l * 2];
                v1 += red[sl * 129 + l * 2 + 1];
            }
            int dg = e1 - e0;
            float inv = 1.f / (float)(dg > 0 ? dg : 1);
            u32 outw = (u32)f2bf(v0 * inv) | ((u32)f2bf(v1 * inv) << 16);
            int byte = (nl * 256 + l * 4) ^ ((nl & 7) << 4);
            *(u32*)((char*)aggl + byte) = outw;
        }
    }

    // ---- Phase B ----
    const int lr = l & 15, kb = l >> 4;
    const int row = rbase + lr;
    const int rowc = row < NN ? row : NN - 1;

    // GEMM1: K=256 over [state_h(global), aggl(LDS)]
    f32x4 acc1[8] = {};
#pragma unroll
    for (int ks = 0; ks < 8; ++ks) {
        short8 a;
        if (ks < 4) {
            a = *(const short8*)(state_h + (size_t)rowc * 128 + ks * 32 + kb * 8);
        } else {
            int byte = (lr * 256 + (ks - 4) * 64 + kb * 16) ^ ((lr & 7) << 4);
            a = *(const short8*)((char*)aggl + byte);
        }
        const u16* bp = packed + W1OFF + (size_t)(ks * 512 + l) * 8;
#pragma unroll
        for (int nt = 0; nt < 8; ++nt) {
            short8 b = *(const short8*)(bp + nt * 512);
            acc1[nt] = mfma16(a, b, acc1[nt]);
        }
    }
    // h = relu(acc1 + b1) -> stage (overlays red; phase A done for this wave)
#pragma unroll
    for (int nt = 0; nt < 8; ++nt) {
        int col = nt * 16 + lr;
        float b1v = up_b1[col];
#pragma unroll
        for (int j = 0; j < 4; ++j) {
            int rl = kb * 4 + j;
            float v = acc1[nt][j] + b1v;
            v = v > 0.f ? v : 0.f;
            int byte = (rl * 256 + col * 2) ^ ((rl & 7) << 4);
            *(u16*)((char*)stage + byte) = f2bf(v);
        }
    }
    // GEMM2: delta = h @ W2
    f32x4 acc2[8] = {};
#pragma unroll
    for (int ks = 0; ks < 4; ++ks) {
        int byte = (lr * 256 + ks * 64 + kb * 16) ^ ((lr & 7) << 4);
        short8 a = *(const short8*)((char*)stage + byte);
        const u16* bp = packed + W2OFF + (size_t)(ks * 512 + l) * 8;
#pragma unroll
        for (int nt = 0; nt < 8; ++nt) {
            short8 b = *(const short8*)(bp + nt * 512);
            acc2[nt] = mfma16(a, b, acc2[nt]);
        }
    }
    // state += delta + b2 ; stage <- state_new (bf16)
#pragma unroll
    for (int nt = 0; nt < 8; ++nt) {
        int col = nt * 16 + lr;
        float b2v = up_b2[col];
#pragma unroll
        for (int j = 0; j < 4; ++j) {
            int rl = kb * 4 + j;
            int r = rbase + rl;
            int rc = r < NN ? r : NN - 1;
            float snew = state_f[(size_t)rc * 128 + col] + acc2[nt][j] + b2v;
            u16 hb = f2bf(snew);
            if (r < NN) {
                state_f[(size_t)r * 128 + col] = snew;
                state_h[(size_t)r * 128 + col] = hb;
            }
            int byte = (rl * 256 + col * 2) ^ ((rl & 7) << 4);
            *(u16*)((char*)stage + byte) = hb;
        }
    }
    // GEMM3: swb_out = state_new @ Ws + msg_b
    f32x4 acc3[8] = {};
#pragma unroll
    for (int ks = 0; ks < 4; ++ks) {
        int byte = (lr * 256 + ks * 64 + kb * 16) ^ ((lr & 7) << 4);
        short8 a = *(const short8*)((char*)stage + byte);
        const u16* bp = packed + WSOFF + (size_t)(ks * 512 + l) * 8;
#pragma unroll
        for (int nt = 0; nt < 8; ++nt) {
            short8 b = *(const short8*)(bp + nt * 512);
            acc3[nt] = mfma16(a, b, acc3[nt]);
        }
    }
#pragma unroll
    for (int nt = 0; nt < 8; ++nt) {
        int col = nt * 16 + lr;
        float bias = msg_b[col];
#pragma unroll
        for (int j = 0; j < 4; ++j) {
            int r = rbase + kb * 4 + j;
            if (r < NN) swb_out[(size_t)r * 128 + col] = f2bf(acc3[nt][j] + bias);
        }
    }
}

// ---------------- logits: deterministic batched segment mean over sorted batch ----------------

__global__ void k_logits(const float* __restrict__ state_f, const int* __restrict__ batch,
                         float* __restrict__ out) {
    __shared__ float red[256];
    int b = blockIdx.x, t = threadIdx.x;
    int ch = t & 7, sub = t >> 3;
    int lo = 0, hi = NN;
    while (lo < hi) { int m = (lo + hi) >> 1; if (batch[m] < b) lo = m + 1; else hi = m; }
    int s0 = lo;
    lo = 0; hi = NN;
    while (lo < hi) { int m = (lo + hi) >> 1; if (batch[m] < b + 1) lo = m + 1; else hi = m; }
    int s1 = lo;
    float acc = 0.f;
    for (int n = s0 + sub; n < s1; n += 32)
        acc += state_f[(size_t)n * 128 + 120 + ch];
    red[t] = acc;
    __syncthreads();
    for (int off = 16; off >= 1; off >>= 1) {
        if (sub < off) red[t] += red[t + off * 8];
        __syncthreads();
    }
    if (sub == 0) {
        int c = s1 - s0;
        float cnt = (float)(c > 0 ? c : 1);
        out[b * 8 + ch] = red[ch] / cnt;
    }
}

// ---------------- launch ----------------

extern "C" void kernel_launch(void* const* d_in, const int* in_sizes, int n_in,
                              void* d_out, int out_size, void* d_ws, size_t ws_size,
                              hipStream_t stream) {
    (void)in_sizes; (void)n_in;
    const float* x      = (const float*)d_in[0];
    const int*   eidx   = (const int*)d_in[1];
    const float* eattr  = (const float*)d_in[2];
    const int*   batch  = (const int*)d_in[3];
    const float* enc_w  = (const float*)d_in[4];
    const float* enc_b  = (const float*)d_in[5];
    const float* msg_w  = (const float*)d_in[6];
    const float* msg_b  = (const float*)d_in[7];
    const float* up_w1  = (const float*)d_in[8];
    const float* up_b1  = (const float*)d_in[9];
    const float* up_w2  = (const float*)d_in[10];
    const float* up_b2  = (const float*)d_in[11];
    const int* esrc = eidx;
    const int* edst = eidx + NE;

    char* p = (char*)d_ws;
    size_t off = 0;
    auto carve = [&](size_t bytes) -> char* {
        char* r = p + off;
        off += (bytes + 255) & ~(size_t)255;
        return r;
    };
    float* state_f = (float*)carve((size_t)NN * 128 * 4);
    u16* state_h   = (u16*)carve((size_t)NN * 128 * 2);
    u16* swb0      = (u16*)carve((size_t)NN * 128 * 2);
    u16* swb1      = (u16*)carve((size_t)NN * 128 * 2);
    int2* sse      = (int2*)carve((size_t)NE * 8);
    unsigned char* eaw = (unsigned char*)carve((size_t)NE * 128);
    int* rowptr    = (int*)carve((size_t)(NN + 1) * 4);
    int* cursor    = (int*)carve((size_t)NN * 4);
    int* hist      = (int*)carve((size_t)NN * 4);
    int* sexcl     = (int*)carve((size_t)NN * 4);
    int* bsum      = (int*)carve((size_t)256 * 4);
    u16* packed    = (u16*)carve((size_t)PACKN * 2);
    if (off > ws_size) {
        // sentinel: NaN output tells us the workspace was too small
        hipMemsetAsync(d_out, 0xFF, (size_t)out_size * 4, stream);
        return;
    }

    hipMemsetAsync(hist, 0, (size_t)NN * 4, stream);
    k_hist<<<(NE + 255) / 256, 256, 0, stream>>>(edst, hist);
    k_scanA<<<SCAN_B, 256, 0, stream>>>(hist, sexcl, bsum);
    k_scanB<<<1, 256, 0, stream>>>(bsum);
    k_scanC<<<SCAN_B, 256, 0, stream>>>(sexcl, bsum, rowptr, cursor);
    k_scatter<<<(NE + 255) / 256, 256, 0, stream>>>(esrc, edst, cursor, sse);
    k_eaw<<<NE / 256, 256, 0, stream>>>(sse, eattr, msg_w, eaw);
    k_pack<<<(PACKN + 255) / 256, 256, 0, stream>>>(up_w1, up_w2, msg_w, enc_w, packed);
    k_encode<<<(NN + 63) / 64, 256, 0, stream>>>(x, enc_b, msg_b, packed, state_f, state_h, swb0);
    u16* sin = swb0;
    u16* sout = swb1;
    for (int t = 0; t < T_STEPS; ++t) {
        k_step<<<(NN + 63) / 64, 256, 0, stream>>>(rowptr, sse, eaw, sin,
                                                   up_b1, up_b2, msg_b, packed,
                                                   state_f, state_h, sout);
        u16* tmp = sin; sin = sout; sout = tmp;
    }
    k_logits<<<NB, 256, 0, stream>>>(state_f, batch, (float*)d_out);
}

// Round 10
// 1211.064 us; speedup vs baseline: 1.3484x; 1.3484x over previous
//
#include <hip/hip_runtime.h>
#include <hip/hip_bf16.h>

#define NN 50000
#define NE 800000
#define NB 16
#define T_STEPS 12
#define SCAN_B 196  // ceil(NN/256)
#define EAW_BLOCKS 2048

typedef __attribute__((ext_vector_type(8))) short short8;
typedef __attribute__((ext_vector_type(4))) float f32x4;
typedef __attribute__((ext_vector_type(2))) float f32x2;
typedef unsigned short u16;
typedef unsigned int u32;

__device__ __forceinline__ float bf2f(u32 u) {
    union { u32 i; float f; } v; v.i = u << 16; return v.f;
}
__device__ __forceinline__ u16 f2bf(float f) {
    union { float f; u32 i; } v; v.f = f;
    u32 r = v.i + 0x7fffu + ((v.i >> 16) & 1u);
    return (u16)(r >> 16);
}
__device__ __forceinline__ f32x4 mfma16(short8 a, short8 b, f32x4 c) {
    return __builtin_amdgcn_mfma_f32_16x16x32_bf16(a, b, c, 0, 0, 0);
}

// pack 2 floats -> fp8 e4m3 pair in low 16 bits (HW instruction; OCP on gfx950)
__device__ __forceinline__ u32 pk2_fp8(float o0, float o1) {
#if __has_builtin(__builtin_amdgcn_cvt_pk_fp8_f32)
    return (u32)__builtin_amdgcn_cvt_pk_fp8_f32(o0, o1, 0, false);
#else
    u32 a = 0;
    asm("v_cvt_pk_fp8_f32 %0, %1, %2" : "+v"(a) : "v"(o0), "v"(o1));
    return a;
#endif
}
__device__ __forceinline__ u32 pk4_fp8(float o0, float o1, float o2, float o3) {
    return (pk2_fp8(o0, o1) & 0xffffu) | (pk2_fp8(o2, o3) << 16);
}

// decode 4x fp8 e4m3 from u32
__device__ __forceinline__ void fp8x4f(u32 w, float& f0, float& f1, float& f2, float& f3) {
#if __has_builtin(__builtin_amdgcn_cvt_pk_f32_fp8)
    f32x2 r0 = __builtin_amdgcn_cvt_pk_f32_fp8((int)w, false);
    f32x2 r1 = __builtin_amdgcn_cvt_pk_f32_fp8((int)w, true);
    f0 = r0[0]; f1 = r0[1]; f2 = r1[0]; f3 = r1[1];
#else
    f32x2 r0, r1;
    u32 hi = w >> 16;
    asm("v_cvt_pk_f32_fp8 %0, %1" : "=v"(r0) : "v"(w));
    asm("v_cvt_pk_f32_fp8 %0, %1" : "=v"(r1) : "v"(hi));
    f0 = r0[0]; f1 = r0[1]; f2 = r1[0]; f3 = r1[1];
#endif
}

// packed weight layout (bf16): elem(((ks*8+nt)*64+l)*8+j) = W[ks*32+((l>>4))*8+j][nt*16+(l&15)]
#define W1OFF 0
#define W2OFF 32768
#define WSOFF 49152
#define ENCOFF 65536
#define PACKN 73728

// ---------------- setup kernels ----------------

__global__ void k_hist(const int* __restrict__ dst, int* __restrict__ hist) {
    int e = blockIdx.x * 256 + threadIdx.x;
    if (e < NE) atomicAdd(&hist[dst[e]], 1);
}

__global__ void k_scanA(const int* __restrict__ hist, int* __restrict__ excl,
                        int* __restrict__ bsum) {
    __shared__ int sh[256];
    int t = threadIdx.x, b = blockIdx.x;
    int idx = b * 256 + t;
    int v = (idx < NN) ? hist[idx] : 0;
    sh[t] = v;
    __syncthreads();
    for (int off = 1; off < 256; off <<= 1) {
        int add = (t >= off) ? sh[t - off] : 0;
        __syncthreads();
        sh[t] += add;
        __syncthreads();
    }
    if (idx < NN) excl[idx] = sh[t] - v;
    if (t == 255) bsum[b] = sh[255];
}

__global__ void k_scanB(int* __restrict__ bsum) {
    __shared__ int sh[256];
    int t = threadIdx.x;
    int v = (t < SCAN_B) ? bsum[t] : 0;
    sh[t] = v;
    __syncthreads();
    for (int off = 1; off < 256; off <<= 1) {
        int add = (t >= off) ? sh[t - off] : 0;
        __syncthreads();
        sh[t] += add;
        __syncthreads();
    }
    if (t < SCAN_B) bsum[t] = sh[t] - v;  // exclusive
}

__global__ void k_scanC(const int* __restrict__ excl, const int* __restrict__ bsum,
                        int* __restrict__ rowptr, int* __restrict__ cursor) {
    int idx = blockIdx.x * 256 + threadIdx.x;
    if (idx < NN) {
        int r = excl[idx] + bsum[blockIdx.x];
        rowptr[idx] = r;
        cursor[idx] = r;
    }
    if (idx == 0) rowptr[NN] = NE;
}

// scatter (src id + bf16 edge-attr) into CSR order; scattered stores are
// fire-and-forget — this kernel is atomic-latency-bound, stores ~free.
__global__ void k_scatter(const int* __restrict__ src, const int* __restrict__ dst,
                          const float* __restrict__ eattr, int* __restrict__ cursor,
                          int* __restrict__ ssrc, u16* __restrict__ ea8) {
    int e = blockIdx.x * 256 + threadIdx.x;
    if (e >= NE) return;
    int d = dst[e];
    int pos = atomicAdd(&cursor[d], 1);
    ssrc[pos] = src[e];
    const float* ap = eattr + (size_t)e * 8;
    uint4 w;
    w.x = (u32)f2bf(ap[0]) | ((u32)f2bf(ap[1]) << 16);
    w.y = (u32)f2bf(ap[2]) | ((u32)f2bf(ap[3]) << 16);
    w.z = (u32)f2bf(ap[4]) | ((u32)f2bf(ap[5]) << 16);
    w.w = (u32)f2bf(ap[6]) | ((u32)f2bf(ap[7]) << 16);
    *(uint4*)(ea8 + (size_t)pos * 8) = w;
}

// eaw[p][c] = fp8( sum_k ea8[p][k] * msg_w[128+k][c] ) — fully coalesced stream:
// ea8 read CSR-ordered (16-lane broadcast per edge), eaw written contiguously.
// weights in VGPRs (w[8][8] = 64 regs); grid-stride with prefetch; no LDS.
__global__ __launch_bounds__(256) void k_eaw(
    const u16* __restrict__ ea8, const float* __restrict__ msg_w,
    unsigned char* __restrict__ eaw) {
    const int tid = threadIdx.x;
    const int hex = tid & 15;   // channel slice [hex*8, hex*8+8)
    const int esub = tid >> 4;  // 0..15
    float w[8][8];
#pragma unroll
    for (int k = 0; k < 8; ++k) {
        float4 v0 = *(const float4*)(msg_w + (size_t)(128 + k) * 128 + hex * 8);
        float4 v1 = *(const float4*)(msg_w + (size_t)(128 + k) * 128 + hex * 8 + 4);
        w[k][0] = v0.x; w[k][1] = v0.y; w[k][2] = v0.z; w[k][3] = v0.w;
        w[k][4] = v1.x; w[k][5] = v1.y; w[k][6] = v1.z; w[k][7] = v1.w;
    }
    int p = blockIdx.x * 16 + esub;
    if (p >= NE) return;
    uint4 ev = *(const uint4*)(ea8 + (size_t)p * 8);
    while (true) {
        int pn = p + EAW_BLOCKS * 16;
        bool more = pn < NE;
        uint4 evn;
        if (more) evn = *(const uint4*)(ea8 + (size_t)pn * 8);
        float ef[8];
        ef[0] = bf2f(ev.x & 0xffffu); ef[1] = bf2f(ev.x >> 16);
        ef[2] = bf2f(ev.y & 0xffffu); ef[3] = bf2f(ev.y >> 16);
        ef[4] = bf2f(ev.z & 0xffffu); ef[5] = bf2f(ev.z >> 16);
        ef[6] = bf2f(ev.w & 0xffffu); ef[7] = bf2f(ev.w >> 16);
        float o[8];
#pragma unroll
        for (int c = 0; c < 8; ++c) o[c] = ef[0] * w[0][c];
#pragma unroll
        for (int k = 1; k < 8; ++k)
#pragma unroll
            for (int c = 0; c < 8; ++c) o[c] += ef[k] * w[k][c];
        uint2 q;
        q.x = pk4_fp8(o[0], o[1], o[2], o[3]);
        q.y = pk4_fp8(o[4], o[5], o[6], o[7]);
        *(uint2*)(eaw + (size_t)p * 128 + hex * 8) = q;
        if (!more) break;
        p = pn;
        ev = evn;
    }
}

__global__ void k_pack(const float* __restrict__ up_w1, const float* __restrict__ up_w2,
                       const float* __restrict__ msg_w, const float* __restrict__ enc_w,
                       u16* __restrict__ packed) {
    int idx = blockIdx.x * 256 + threadIdx.x;
    if (idx >= PACKN) return;
    const float* srcp; int local;
    if (idx < W2OFF)        { srcp = up_w1; local = idx; }
    else if (idx < WSOFF)   { srcp = up_w2; local = idx - W2OFF; }
    else if (idx < ENCOFF)  { srcp = msg_w; local = idx - WSOFF; }   // rows 0..127 (state part)
    else                    { srcp = enc_w; local = idx - ENCOFF; }
    int j = local & 7;
    int l = (local >> 3) & 63;
    int ntks = local >> 9;
    int nt = ntks & 7;
    int ks = ntks >> 3;
    int krow = ks * 32 + (l >> 4) * 8 + j;
    int col = nt * 16 + (l & 15);
    packed[idx] = f2bf(srcp[krow * 128 + col]);
}

// ---------------- encoder: state = relu(x@enc_w+enc_b); SW = state@Ws + msg_b ----------------

__global__ __launch_bounds__(256) void k_encode(
    const float* __restrict__ x, const float* __restrict__ enc_b,
    const float* __restrict__ msg_b, const u16* __restrict__ packed,
    float* __restrict__ state_f, u16* __restrict__ state_h, u16* __restrict__ swb) {
    __shared__ u16 stage[4][2048];
    const int wv = threadIdx.x >> 6, l = threadIdx.x & 63;
    const int lr = l & 15, kb = l >> 4;
    const int rb = blockIdx.x * 64 + wv * 16;
    const int row = rb + lr;
    const int rowc = row < NN ? row : NN - 1;

    f32x4 acc[8] = {};
#pragma unroll
    for (int ks = 0; ks < 2; ++ks) {
        const float* ap = x + (size_t)rowc * 64 + ks * 32 + kb * 8;
        float4 a0 = *(const float4*)ap;
        float4 a1 = *(const float4*)(ap + 4);
        short8 a;
        a[0] = (short)f2bf(a0.x); a[1] = (short)f2bf(a0.y);
        a[2] = (short)f2bf(a0.z); a[3] = (short)f2bf(a0.w);
        a[4] = (short)f2bf(a1.x); a[5] = (short)f2bf(a1.y);
        a[6] = (short)f2bf(a1.z); a[7] = (short)f2bf(a1.w);
        const u16* bp = packed + ENCOFF + (size_t)(ks * 512 + l) * 8;
#pragma unroll
        for (int nt = 0; nt < 8; ++nt) {
            short8 b = *(const short8*)(bp + nt * 512);
            acc[nt] = mfma16(a, b, acc[nt]);
        }
    }
#pragma unroll
    for (int nt = 0; nt < 8; ++nt) {
        int col = nt * 16 + lr;
        float bias = enc_b[col];
#pragma unroll
        for (int j = 0; j < 4; ++j) {
            int rl = kb * 4 + j;
            int r = rb + rl;
            float v = acc[nt][j] + bias;
            v = v > 0.f ? v : 0.f;
            u16 h = f2bf(v);
            if (r < NN) {
                state_f[(size_t)r * 128 + col] = v;
                state_h[(size_t)r * 128 + col] = h;
            }
            int byte = (rl * 256 + col * 2) ^ ((rl & 7) << 4);
            *(u16*)((char*)stage[wv] + byte) = h;
        }
    }
    f32x4 acc3[8] = {};
#pragma unroll
    for (int ks = 0; ks < 4; ++ks) {
        int byte = (lr * 256 + ks * 64 + kb * 16) ^ ((lr & 7) << 4);
        short8 a = *(const short8*)((char*)stage[wv] + byte);
        const u16* bp = packed + WSOFF + (size_t)(ks * 512 + l) * 8;
#pragma unroll
        for (int nt = 0; nt < 8; ++nt) {
            short8 b = *(const short8*)(bp + nt * 512);
            acc3[nt] = mfma16(a, b, acc3[nt]);
        }
    }
#pragma unroll
    for (int nt = 0; nt < 8; ++nt) {
        int col = nt * 16 + lr;
        float bias = msg_b[col];
#pragma unroll
        for (int j = 0; j < 4; ++j) {
            int r = rb + kb * 4 + j;
            if (r < NN) swb[(size_t)r * 128 + col] = f2bf(acc3[nt][j] + bias);
        }
    }
}

// ---------------- edge kernel: agg[n] = mean_e relu(SW[src_e] + EAW[e]) ----------------
// 2 nodes/wave x 4 edge-slots x 8 lanes (16 ch/lane, bf16 gathers).
// 8 independent gather chains per wave + ssrc prefetch; slot reduction via padded LDS.

__global__ __launch_bounds__(256) void k_edge(
    const int* __restrict__ rowptr, const int* __restrict__ ssrc,
    const unsigned char* __restrict__ eaw, const u16* __restrict__ swb,
    u16* __restrict__ aggb) {
    __shared__ float red[4][2][4][129];  // [wave][node][slot][ch padded]
    const int wv = threadIdx.x >> 6, l = threadIdx.x & 63;
    const int half = l >> 5;          // node within wave
    const int slot = (l >> 3) & 3;    // edge slot
    const int g = l & 7;              // 16-ch group
    const int n = blockIdx.x * 8 + wv * 2 + half;
    if (n >= NN) return;
    const int e0 = rowptr[n], e1 = rowptr[n + 1];
    float acc[16];
#pragma unroll
    for (int c = 0; c < 16; ++c) acc[c] = 0.f;

    int i = e0 + slot;
    int s = (i < e1) ? ssrc[i] : 0;
    while (i < e1) {
        int inext = i + 4;
        int snext = (inext < e1) ? ssrc[inext] : 0;
        uint4 q = *(const uint4*)(eaw + (size_t)i * 128 + g * 16);
        const u16* sp = swb + (size_t)s * 128 + g * 16;
        uint4 sa = *(const uint4*)sp;
        uint4 sb = *(const uint4*)(sp + 8);
        float ef[16];
        fp8x4f(q.x, ef[0], ef[1], ef[2], ef[3]);
        fp8x4f(q.y, ef[4], ef[5], ef[6], ef[7]);
        fp8x4f(q.z, ef[8], ef[9], ef[10], ef[11]);
        fp8x4f(q.w, ef[12], ef[13], ef[14], ef[15]);
        u32 sw[8] = {sa.x, sa.y, sa.z, sa.w, sb.x, sb.y, sb.z, sb.w};
#pragma unroll
        for (int h = 0; h < 8; ++h) {
            union { u32 i; float f; } vlo, vhi;
            vlo.i = sw[h] << 16;
            vhi.i = sw[h] & 0xffff0000u;
            float m0 = vlo.f + ef[2 * h];
            float m1 = vhi.f + ef[2 * h + 1];
            acc[2 * h]     += m0 > 0.f ? m0 : 0.f;
            acc[2 * h + 1] += m1 > 0.f ? m1 : 0.f;
        }
        i = inext;
        s = snext;
    }
    // per-slot partials -> LDS (wave-local, in-order per wave; no barrier)
    float* rp = &red[wv][half][slot][g * 16];
#pragma unroll
    for (int c = 0; c < 16; c += 4) {
        f32x4 v = {acc[c], acc[c + 1], acc[c + 2], acc[c + 3]};
        *(f32x4*)(rp + c) = v;
    }
    // reduce 4 slots; lane lo handles 4 channels
    const int lo = l & 31;
    const int ch = lo * 4;
    f32x4 sum = *(const f32x4*)&red[wv][half][0][ch];
#pragma unroll
    for (int sl = 1; sl < 4; ++sl) {
        f32x4 v = *(const f32x4*)&red[wv][half][sl][ch];
        sum[0] += v[0]; sum[1] += v[1]; sum[2] += v[2]; sum[3] += v[3];
    }
    int dg = e1 - e0;
    float inv = 1.f / (float)(dg > 0 ? dg : 1);
    uint2 outw;
    outw.x = (u32)f2bf(sum[0] * inv) | ((u32)f2bf(sum[1] * inv) << 16);
    outw.y = (u32)f2bf(sum[2] * inv) | ((u32)f2bf(sum[3] * inv) << 16);
    *(uint2*)(aggb + (size_t)n * 128 + ch) = outw;
}

// ---------------- update kernel (R=2 row tiles/wave, direct global B): ----------------
// h=relu([state,agg]@W1+b1); state+=h@W2+b2; SW=state@Ws+msg_b

__global__ __launch_bounds__(256) void k_update(
    const float* __restrict__ up_b1, const float* __restrict__ up_b2,
    const float* __restrict__ msg_b, const u16* __restrict__ packed,
    const u16* __restrict__ aggb, float* __restrict__ state_f,
    u16* __restrict__ state_h, u16* __restrict__ swb) {
    __shared__ u16 stage[4][2][2048];
    const int wv = threadIdx.x >> 6, l = threadIdx.x & 63;
    const int lr = l & 15, kb = l >> 4;
    const int rbase = blockIdx.x * 128 + wv * 32;

    // GEMM1: K=256 over [state_h, aggb], 2 row tiles
    f32x4 acc[2][8] = {};
#pragma unroll
    for (int ks = 0; ks < 8; ++ks) {
        short8 a[2];
#pragma unroll
        for (int rt = 0; rt < 2; ++rt) {
            int row = rbase + rt * 16 + lr;
            int rowc = row < NN ? row : NN - 1;
            const u16* abase = (ks < 4)
                ? (state_h + (size_t)rowc * 128 + ks * 32 + kb * 8)
                : (aggb + (size_t)rowc * 128 + (ks - 4) * 32 + kb * 8);
            a[rt] = *(const short8*)abase;
        }
        const u16* bp = packed + W1OFF + (size_t)(ks * 512 + l) * 8;
#pragma unroll
        for (int nt = 0; nt < 8; ++nt) {
            short8 b = *(const short8*)(bp + nt * 512);
            acc[0][nt] = mfma16(a[0], b, acc[0][nt]);
            acc[1][nt] = mfma16(a[1], b, acc[1][nt]);
        }
    }
    // h = relu(acc + b1) -> stage
#pragma unroll
    for (int nt = 0; nt < 8; ++nt) {
        int col = nt * 16 + lr;
        float b1v = up_b1[col];
#pragma unroll
        for (int rt = 0; rt < 2; ++rt) {
#pragma unroll
            for (int j = 0; j < 4; ++j) {
                int rl = kb * 4 + j;
                float v = acc[rt][nt][j] + b1v;
                v = v > 0.f ? v : 0.f;
                int byte = (rl * 256 + col * 2) ^ ((rl & 7) << 4);
                *(u16*)((char*)stage[wv][rt] + byte) = f2bf(v);
            }
        }
    }
    // GEMM2: delta = h @ W2
    f32x4 acc2[2][8] = {};
#pragma unroll
    for (int ks = 0; ks < 4; ++ks) {
        int byte = (lr * 256 + ks * 64 + kb * 16) ^ ((lr & 7) << 4);
        short8 a[2];
        a[0] = *(const short8*)((char*)stage[wv][0] + byte);
        a[1] = *(const short8*)((char*)stage[wv][1] + byte);
        const u16* bp = packed + W2OFF + (size_t)(ks * 512 + l) * 8;
#pragma unroll
        for (int nt = 0; nt < 8; ++nt) {
            short8 b = *(const short8*)(bp + nt * 512);
            acc2[0][nt] = mfma16(a[0], b, acc2[0][nt]);
            acc2[1][nt] = mfma16(a[1], b, acc2[1][nt]);
        }
    }
    // state += delta + b2 ; stage <- state_new (bf16) [wave-local, in-order]
#pragma unroll
    for (int rt = 0; rt < 2; ++rt) {
#pragma unroll
        for (int nt = 0; nt < 8; ++nt) {
            int col = nt * 16 + lr;
            float b2v = up_b2[col];
#pragma unroll
            for (int j = 0; j < 4; ++j) {
                int rl = kb * 4 + j;
                int r = rbase + rt * 16 + rl;
                int rc = r < NN ? r : NN - 1;
                float snew = state_f[(size_t)rc * 128 + col] + acc2[rt][nt][j] + b2v;
                u16 hb = f2bf(snew);
                if (r < NN) {
                    state_f[(size_t)r * 128 + col] = snew;
                    state_h[(size_t)r * 128 + col] = hb;
                }
                int byte = (rl * 256 + col * 2) ^ ((rl & 7) << 4);
                *(u16*)((char*)stage[wv][rt] + byte) = hb;
            }
        }
    }
    // GEMM3: SW = state_new @ Ws + msg_b
    f32x4 acc3[2][8] = {};
#pragma unroll
    for (int ks = 0; ks < 4; ++ks) {
        int byte = (lr * 256 + ks * 64 + kb * 16) ^ ((lr & 7) << 4);
        short8 a[2];
        a[0] = *(const short8*)((char*)stage[wv][0] + byte);
        a[1] = *(const short8*)((char*)stage[wv][1] + byte);
        const u16* bp = packed + WSOFF + (size_t)(ks * 512 + l) * 8;
#pragma unroll
        for (int nt = 0; nt < 8; ++nt) {
            short8 b = *(const short8*)(bp + nt * 512);
            acc3[0][nt] = mfma16(a[0], b, acc3[0][nt]);
            acc3[1][nt] = mfma16(a[1], b, acc3[1][nt]);
        }
    }
#pragma unroll
    for (int rt = 0; rt < 2; ++rt) {
#pragma unroll
        for (int nt = 0; nt < 8; ++nt) {
            int col = nt * 16 + lr;
            float bias = msg_b[col];
#pragma unroll
            for (int j = 0; j < 4; ++j) {
                int r = rbase + rt * 16 + kb * 4 + j;
                if (r < NN) swb[(size_t)r * 128 + col] = f2bf(acc3[rt][nt][j] + bias);
            }
        }
    }
}

// ---------------- logits: deterministic batched segment mean over sorted batch ----------------

__global__ void k_logits(const float* __restrict__ state_f, const int* __restrict__ batch,
                         float* __restrict__ out) {
    __shared__ float red[256];
    int b = blockIdx.x, t = threadIdx.x;
    int ch = t & 7, sub = t >> 3;
    int lo = 0, hi = NN;
    while (lo < hi) { int m = (lo + hi) >> 1; if (batch[m] < b) lo = m + 1; else hi = m; }
    int s0 = lo;
    lo = 0; hi = NN;
    while (lo < hi) { int m = (lo + hi) >> 1; if (batch[m] < b + 1) lo = m + 1; else hi = m; }
    int s1 = lo;
    float acc = 0.f;
    for (int n = s0 + sub; n < s1; n += 32)
        acc += state_f[(size_t)n * 128 + 120 + ch];
    red[t] = acc;
    __syncthreads();
    for (int off = 16; off >= 1; off >>= 1) {
        if (sub < off) red[t] += red[t + off * 8];
        __syncthreads();
    }
    if (sub == 0) {
        int c = s1 - s0;
        float cnt = (float)(c > 0 ? c : 1);
        out[b * 8 + ch] = red[ch] / cnt;
    }
}

// ---------------- launch ----------------

extern "C" void kernel_launch(void* const* d_in, const int* in_sizes, int n_in,
                              void* d_out, int out_size, void* d_ws, size_t ws_size,
                              hipStream_t stream) {
    (void)in_sizes; (void)n_in;
    const float* x      = (const float*)d_in[0];
    const int*   eidx   = (const int*)d_in[1];
    const float* eattr  = (const float*)d_in[2];
    const int*   batch  = (const int*)d_in[3];
    const float* enc_w  = (const float*)d_in[4];
    const float* enc_b  = (const float*)d_in[5];
    const float* msg_w  = (const float*)d_in[6];
    const float* msg_b  = (const float*)d_in[7];
    const float* up_w1  = (const float*)d_in[8];
    const float* up_b1  = (const float*)d_in[9];
    const float* up_w2  = (const float*)d_in[10];
    const float* up_b2  = (const float*)d_in[11];
    const int* esrc = eidx;
    const int* edst = eidx + NE;

    char* p = (char*)d_ws;
    size_t off = 0;
    auto carve = [&](size_t bytes) -> char* {
        char* r = p + off;
        off += (bytes + 255) & ~(size_t)255;
        return r;
    };
    float* state_f = (float*)carve((size_t)NN * 128 * 4);
    u16* state_h   = (u16*)carve((size_t)NN * 128 * 2);
    u16* aggb      = (u16*)carve((size_t)NN * 128 * 2);
    u16* swb       = (u16*)carve((size_t)NN * 128 * 2);
    int* ssrc      = (int*)carve((size_t)NE * 4);
    u16* ea8       = (u16*)carve((size_t)NE * 8 * 2);
    unsigned char* eaw = (unsigned char*)carve((size_t)NE * 128);
    int* rowptr    = (int*)carve((size_t)(NN + 1) * 4);
    int* cursor    = (int*)carve((size_t)NN * 4);
    int* hist      = (int*)carve((size_t)NN * 4);
    int* sexcl     = (int*)carve((size_t)NN * 4);
    int* bsum      = (int*)carve((size_t)256 * 4);
    u16* packed    = (u16*)carve((size_t)PACKN * 2);
    if (off > ws_size) {
        // sentinel: NaN output tells us the workspace was too small
        hipMemsetAsync(d_out, 0xFF, (size_t)out_size * 4, stream);
        return;
    }

    hipMemsetAsync(hist, 0, (size_t)NN * 4, stream);
    k_hist<<<(NE + 255) / 256, 256, 0, stream>>>(edst, hist);
    k_scanA<<<SCAN_B, 256, 0, stream>>>(hist, sexcl, bsum);
    k_scanB<<<1, 256, 0, stream>>>(bsum);
    k_scanC<<<SCAN_B, 256, 0, stream>>>(sexcl, bsum, rowptr, cursor);
    k_scatter<<<(NE + 255) / 256, 256, 0, stream>>>(esrc, edst, eattr, cursor, ssrc, ea8);
    k_eaw<<<EAW_BLOCKS, 256, 0, stream>>>(ea8, msg_w, eaw);
    k_pack<<<(PACKN + 255) / 256, 256, 0, stream>>>(up_w1, up_w2, msg_w, enc_w, packed);
    k_encode<<<(NN + 63) / 64, 256, 0, stream>>>(x, enc_b, msg_b, packed, state_f, state_h, swb);
    for (int t = 0; t < T_STEPS; ++t) {
        k_edge<<<(NN + 7) / 8, 256, 0, stream>>>(rowptr, ssrc, eaw, swb, aggb);
        k_update<<<(NN + 127) / 128, 256, 0, stream>>>(up_b1, up_b2, msg_b, packed, aggb,
                                                       state_f, state_h, swb);
    }
    k_logits<<<NB, 256, 0, stream>>>(state_f, batch, (float*)d_out);
}

// Round 11
// 1135.430 us; speedup vs baseline: 1.4382x; 1.0666x over previous
//
#include <hip/hip_runtime.h>
#include <hip/hip_bf16.h>

#define NN 50000
#define NE 800000
#define NB 16
#define T_STEPS 12
#define SCAN_B 196  // ceil(NN/256)
#define EAW_BLOCKS 2048

typedef __attribute__((ext_vector_type(8))) short short8;
typedef __attribute__((ext_vector_type(4))) float f32x4;
typedef __attribute__((ext_vector_type(2))) float f32x2;
typedef unsigned short u16;
typedef unsigned int u32;

__device__ __forceinline__ float bf2f(u32 u) {
    union { u32 i; float f; } v; v.i = u << 16; return v.f;
}
__device__ __forceinline__ u16 f2bf(float f) {
    union { float f; u32 i; } v; v.f = f;
    u32 r = v.i + 0x7fffu + ((v.i >> 16) & 1u);
    return (u16)(r >> 16);
}
__device__ __forceinline__ f32x4 mfma16(short8 a, short8 b, f32x4 c) {
    return __builtin_amdgcn_mfma_f32_16x16x32_bf16(a, b, c, 0, 0, 0);
}

// pack 2 floats -> fp8 e4m3 pair in low 16 bits (HW instruction; OCP on gfx950)
__device__ __forceinline__ u32 pk2_fp8(float o0, float o1) {
#if __has_builtin(__builtin_amdgcn_cvt_pk_fp8_f32)
    return (u32)__builtin_amdgcn_cvt_pk_fp8_f32(o0, o1, 0, false);
#else
    u32 a = 0;
    asm("v_cvt_pk_fp8_f32 %0, %1, %2" : "+v"(a) : "v"(o0), "v"(o1));
    return a;
#endif
}
__device__ __forceinline__ u32 pk4_fp8(float o0, float o1, float o2, float o3) {
    return (pk2_fp8(o0, o1) & 0xffffu) | (pk2_fp8(o2, o3) << 16);
}

// decode 4x fp8 e4m3 from u32
__device__ __forceinline__ void fp8x4f(u32 w, float& f0, float& f1, float& f2, float& f3) {
#if __has_builtin(__builtin_amdgcn_cvt_pk_f32_fp8)
    f32x2 r0 = __builtin_amdgcn_cvt_pk_f32_fp8((int)w, false);
    f32x2 r1 = __builtin_amdgcn_cvt_pk_f32_fp8((int)w, true);
    f0 = r0[0]; f1 = r0[1]; f2 = r1[0]; f3 = r1[1];
#else
    f32x2 r0, r1;
    u32 hi = w >> 16;
    asm("v_cvt_pk_f32_fp8 %0, %1" : "=v"(r0) : "v"(w));
    asm("v_cvt_pk_f32_fp8 %0, %1" : "=v"(r1) : "v"(hi));
    f0 = r0[0]; f1 = r0[1]; f2 = r1[0]; f3 = r1[1];
#endif
}

// packed weight layout (bf16): elem(((ks*8+nt)*64+l)*8+j) = W[ks*32+((l>>4))*8+j][nt*16+(l&15)]
#define W1OFF 0
#define W2OFF 32768
#define WSOFF 49152
#define ENCOFF 65536
#define PACKN 73728

// ---------------- setup kernels ----------------

__global__ void k_hist(const int* __restrict__ dst, int* __restrict__ hist) {
    int e = blockIdx.x * 256 + threadIdx.x;
    if (e < NE) atomicAdd(&hist[dst[e]], 1);
}

__global__ void k_scanA(const int* __restrict__ hist, int* __restrict__ excl,
                        int* __restrict__ bsum) {
    __shared__ int sh[256];
    int t = threadIdx.x, b = blockIdx.x;
    int idx = b * 256 + t;
    int v = (idx < NN) ? hist[idx] : 0;
    sh[t] = v;
    __syncthreads();
    for (int off = 1; off < 256; off <<= 1) {
        int add = (t >= off) ? sh[t - off] : 0;
        __syncthreads();
        sh[t] += add;
        __syncthreads();
    }
    if (idx < NN) excl[idx] = sh[t] - v;
    if (t == 255) bsum[b] = sh[255];
}

__global__ void k_scanB(int* __restrict__ bsum) {
    __shared__ int sh[256];
    int t = threadIdx.x;
    int v = (t < SCAN_B) ? bsum[t] : 0;
    sh[t] = v;
    __syncthreads();
    for (int off = 1; off < 256; off <<= 1) {
        int add = (t >= off) ? sh[t - off] : 0;
        __syncthreads();
        sh[t] += add;
        __syncthreads();
    }
    if (t < SCAN_B) bsum[t] = sh[t] - v;  // exclusive
}

__global__ void k_scanC(const int* __restrict__ excl, const int* __restrict__ bsum,
                        int* __restrict__ rowptr, int* __restrict__ cursor) {
    int idx = blockIdx.x * 256 + threadIdx.x;
    if (idx < NN) {
        int r = excl[idx] + bsum[blockIdx.x];
        rowptr[idx] = r;
        cursor[idx] = r;
    }
    if (idx == 0) rowptr[NN] = NE;
}

// scatter (src id + bf16 edge-attr) into CSR order; atomic-latency-bound, stores ~free.
__global__ void k_scatter(const int* __restrict__ src, const int* __restrict__ dst,
                          const float* __restrict__ eattr, int* __restrict__ cursor,
                          int* __restrict__ ssrc, u16* __restrict__ ea8) {
    int e = blockIdx.x * 256 + threadIdx.x;
    if (e >= NE) return;
    int d = dst[e];
    int pos = atomicAdd(&cursor[d], 1);
    ssrc[pos] = src[e];
    const float* ap = eattr + (size_t)e * 8;
    uint4 w;
    w.x = (u32)f2bf(ap[0]) | ((u32)f2bf(ap[1]) << 16);
    w.y = (u32)f2bf(ap[2]) | ((u32)f2bf(ap[3]) << 16);
    w.z = (u32)f2bf(ap[4]) | ((u32)f2bf(ap[5]) << 16);
    w.w = (u32)f2bf(ap[6]) | ((u32)f2bf(ap[7]) << 16);
    *(uint4*)(ea8 + (size_t)pos * 8) = w;
}

// eaw[p][c] = fp8( sum_k ea8[p][k] * msg_w[128+k][c] ) — fully coalesced stream.
__global__ __launch_bounds__(256) void k_eaw(
    const u16* __restrict__ ea8, const float* __restrict__ msg_w,
    unsigned char* __restrict__ eaw) {
    const int tid = threadIdx.x;
    const int hex = tid & 15;   // channel slice [hex*8, hex*8+8)
    const int esub = tid >> 4;  // 0..15
    float w[8][8];
#pragma unroll
    for (int k = 0; k < 8; ++k) {
        float4 v0 = *(const float4*)(msg_w + (size_t)(128 + k) * 128 + hex * 8);
        float4 v1 = *(const float4*)(msg_w + (size_t)(128 + k) * 128 + hex * 8 + 4);
        w[k][0] = v0.x; w[k][1] = v0.y; w[k][2] = v0.z; w[k][3] = v0.w;
        w[k][4] = v1.x; w[k][5] = v1.y; w[k][6] = v1.z; w[k][7] = v1.w;
    }
    int p = blockIdx.x * 16 + esub;
    if (p >= NE) return;
    uint4 ev = *(const uint4*)(ea8 + (size_t)p * 8);
    while (true) {
        int pn = p + EAW_BLOCKS * 16;
        bool more = pn < NE;
        uint4 evn;
        if (more) evn = *(const uint4*)(ea8 + (size_t)pn * 8);
        float ef[8];
        ef[0] = bf2f(ev.x & 0xffffu); ef[1] = bf2f(ev.x >> 16);
        ef[2] = bf2f(ev.y & 0xffffu); ef[3] = bf2f(ev.y >> 16);
        ef[4] = bf2f(ev.z & 0xffffu); ef[5] = bf2f(ev.z >> 16);
        ef[6] = bf2f(ev.w & 0xffffu); ef[7] = bf2f(ev.w >> 16);
        float o[8];
#pragma unroll
        for (int c = 0; c < 8; ++c) o[c] = ef[0] * w[0][c];
#pragma unroll
        for (int k = 1; k < 8; ++k)
#pragma unroll
            for (int c = 0; c < 8; ++c) o[c] += ef[k] * w[k][c];
        uint2 q;
        q.x = pk4_fp8(o[0], o[1], o[2], o[3]);
        q.y = pk4_fp8(o[4], o[5], o[6], o[7]);
        *(uint2*)(eaw + (size_t)p * 128 + hex * 8) = q;
        if (!more) break;
        p = pn;
        ev = evn;
    }
}

__global__ void k_pack(const float* __restrict__ up_w1, const float* __restrict__ up_w2,
                       const float* __restrict__ msg_w, const float* __restrict__ enc_w,
                       u16* __restrict__ packed) {
    int idx = blockIdx.x * 256 + threadIdx.x;
    if (idx >= PACKN) return;
    const float* srcp; int local;
    if (idx < W2OFF)        { srcp = up_w1; local = idx; }
    else if (idx < WSOFF)   { srcp = up_w2; local = idx - W2OFF; }
    else if (idx < ENCOFF)  { srcp = msg_w; local = idx - WSOFF; }   // rows 0..127 (state part)
    else                    { srcp = enc_w; local = idx - ENCOFF; }
    int j = local & 7;
    int l = (local >> 3) & 63;
    int ntks = local >> 9;
    int nt = ntks & 7;
    int ks = ntks >> 3;
    int krow = ks * 32 + (l >> 4) * 8 + j;
    int col = nt * 16 + (l & 15);
    packed[idx] = f2bf(srcp[krow * 128 + col]);
}

// ---------------- encoder: state_h = bf16(relu(x@enc_w+enc_b)); swb = bf16(state@Ws+msg_b) ----------------

__global__ __launch_bounds__(256) void k_encode(
    const float* __restrict__ x, const float* __restrict__ enc_b,
    const float* __restrict__ msg_b, const u16* __restrict__ packed,
    u16* __restrict__ state_h, u16* __restrict__ swb) {
    __shared__ u16 stage[4][2048];
    const int wv = threadIdx.x >> 6, l = threadIdx.x & 63;
    const int lr = l & 15, kb = l >> 4;
    const int rb = blockIdx.x * 64 + wv * 16;
    const int row = rb + lr;
    const int rowc = row < NN ? row : NN - 1;

    f32x4 acc[8] = {};
#pragma unroll
    for (int ks = 0; ks < 2; ++ks) {
        const float* ap = x + (size_t)rowc * 64 + ks * 32 + kb * 8;
        float4 a0 = *(const float4*)ap;
        float4 a1 = *(const float4*)(ap + 4);
        short8 a;
        a[0] = (short)f2bf(a0.x); a[1] = (short)f2bf(a0.y);
        a[2] = (short)f2bf(a0.z); a[3] = (short)f2bf(a0.w);
        a[4] = (short)f2bf(a1.x); a[5] = (short)f2bf(a1.y);
        a[6] = (short)f2bf(a1.z); a[7] = (short)f2bf(a1.w);
        const u16* bp = packed + ENCOFF + (size_t)(ks * 512 + l) * 8;
#pragma unroll
        for (int nt = 0; nt < 8; ++nt) {
            short8 b = *(const short8*)(bp + nt * 512);
            acc[nt] = mfma16(a, b, acc[nt]);
        }
    }
#pragma unroll
    for (int nt = 0; nt < 8; ++nt) {
        int col = nt * 16 + lr;
        float bias = enc_b[col];
#pragma unroll
        for (int j = 0; j < 4; ++j) {
            int rl = kb * 4 + j;
            int r = rb + rl;
            float v = acc[nt][j] + bias;
            v = v > 0.f ? v : 0.f;
            u16 h = f2bf(v);
            if (r < NN) state_h[(size_t)r * 128 + col] = h;
            int byte = (rl * 256 + col * 2) ^ ((rl & 7) << 4);
            *(u16*)((char*)stage[wv] + byte) = h;
        }
    }
    f32x4 acc3[8] = {};
#pragma unroll
    for (int ks = 0; ks < 4; ++ks) {
        int byte = (lr * 256 + ks * 64 + kb * 16) ^ ((lr & 7) << 4);
        short8 a = *(const short8*)((char*)stage[wv] + byte);
        const u16* bp = packed + WSOFF + (size_t)(ks * 512 + l) * 8;
#pragma unroll
        for (int nt = 0; nt < 8; ++nt) {
            short8 b = *(const short8*)(bp + nt * 512);
            acc3[nt] = mfma16(a, b, acc3[nt]);
        }
    }
#pragma unroll
    for (int nt = 0; nt < 8; ++nt) {
        int col = nt * 16 + lr;
        float bias = msg_b[col];
#pragma unroll
        for (int j = 0; j < 4; ++j) {
            int r = rb + kb * 4 + j;
            if (r < NN) swb[(size_t)r * 128 + col] = f2bf(acc3[nt][j] + bias);
        }
    }
}

// ---------------- edge kernel: agg[n] = mean_e relu(SW[src_e] + EAW[e]) ----------------
// 2 nodes/wave x 4 edge-slots x 8 lanes (16 ch/lane, bf16 gathers).
// 2-stage software pipeline: ssrc prefetched 2 iters ahead, eaw+swb DATA 1 iter ahead.

__global__ __launch_bounds__(256) void k_edge(
    const int* __restrict__ rowptr, const int* __restrict__ ssrc,
    const unsigned char* __restrict__ eaw, const u16* __restrict__ swb,
    u16* __restrict__ aggb) {
    __shared__ float red[4][2][4][129];  // [wave][node][slot][ch padded]
    const int wv = threadIdx.x >> 6, l = threadIdx.x & 63;
    const int half = l >> 5;          // node within wave
    const int slot = (l >> 3) & 3;    // edge slot
    const int g = l & 7;              // 16-ch group
    const int n = blockIdx.x * 8 + wv * 2 + half;
    if (n >= NN) return;
    const int e0 = rowptr[n], e1 = rowptr[n + 1];
    float acc[16];
#pragma unroll
    for (int c = 0; c < 16; ++c) acc[c] = 0.f;

    int i = e0 + slot;
    uint4 qc = {0, 0, 0, 0}, sac = {0, 0, 0, 0}, sbc = {0, 0, 0, 0};
    if (i < e1) {
        int sc = ssrc[i];
        qc = *(const uint4*)(eaw + (size_t)i * 128 + g * 16);
        const u16* sp = swb + (size_t)sc * 128 + g * 16;
        sac = *(const uint4*)sp;
        sbc = *(const uint4*)(sp + 8);
    }
    int inext = i + 4;
    int snext = (inext < e1) ? ssrc[inext] : 0;
    while (i < e1) {
        // prefetch iteration i+4 (data) and i+8 (index)
        int i2 = inext + 4;
        int s2 = (i2 < e1) ? ssrc[i2] : 0;
        uint4 qn = {0, 0, 0, 0}, san = {0, 0, 0, 0}, sbn = {0, 0, 0, 0};
        if (inext < e1) {
            qn = *(const uint4*)(eaw + (size_t)inext * 128 + g * 16);
            const u16* sp = swb + (size_t)snext * 128 + g * 16;
            san = *(const uint4*)sp;
            sbn = *(const uint4*)(sp + 8);
        }
        // compute on current staged data
        float ef[16];
        fp8x4f(qc.x, ef[0], ef[1], ef[2], ef[3]);
        fp8x4f(qc.y, ef[4], ef[5], ef[6], ef[7]);
        fp8x4f(qc.z, ef[8], ef[9], ef[10], ef[11]);
        fp8x4f(qc.w, ef[12], ef[13], ef[14], ef[15]);
        u32 sw[8] = {sac.x, sac.y, sac.z, sac.w, sbc.x, sbc.y, sbc.z, sbc.w};
#pragma unroll
        for (int h = 0; h < 8; ++h) {
            union { u32 i; float f; } vlo, vhi;
            vlo.i = sw[h] << 16;
            vhi.i = sw[h] & 0xffff0000u;
            float m0 = vlo.f + ef[2 * h];
            float m1 = vhi.f + ef[2 * h + 1];
            acc[2 * h]     += m0 > 0.f ? m0 : 0.f;
            acc[2 * h + 1] += m1 > 0.f ? m1 : 0.f;
        }
        qc = qn; sac = san; sbc = sbn;
        i = inext;
        inext = i2;
        snext = s2;
    }
    // per-slot partials -> LDS (wave-local, in-order per wave; no barrier)
    float* rp = &red[wv][half][slot][g * 16];
#pragma unroll
    for (int c = 0; c < 16; c += 4) {
        f32x4 v = {acc[c], acc[c + 1], acc[c + 2], acc[c + 3]};
        *(f32x4*)(rp + c) = v;
    }
    // reduce 4 slots; lane lo handles 4 channels
    const int lo = l & 31;
    const int ch = lo * 4;
    f32x4 sum = *(const f32x4*)&red[wv][half][0][ch];
#pragma unroll
    for (int sl = 1; sl < 4; ++sl) {
        f32x4 v = *(const f32x4*)&red[wv][half][sl][ch];
        sum[0] += v[0]; sum[1] += v[1]; sum[2] += v[2]; sum[3] += v[3];
    }
    int dg = e1 - e0;
    float inv = 1.f / (float)(dg > 0 ? dg : 1);
    uint2 outw;
    outw.x = (u32)f2bf(sum[0] * inv) | ((u32)f2bf(sum[1] * inv) << 16);
    outw.y = (u32)f2bf(sum[2] * inv) | ((u32)f2bf(sum[3] * inv) << 16);
    *(uint2*)(aggb + (size_t)n * 128 + ch) = outw;
}

// ---------------- update kernel (R=2 row tiles/wave, bf16 state master): ----------------
// h=relu([state,agg]@W1+b1); state+=h@W2+b2; swb=state@Ws+msg_b

__global__ __launch_bounds__(256) void k_update(
    const float* __restrict__ up_b1, const float* __restrict__ up_b2,
    const float* __restrict__ msg_b, const u16* __restrict__ packed,
    const u16* __restrict__ aggb, u16* __restrict__ state_h,
    u16* __restrict__ swb) {
    __shared__ u16 stage[4][2][2048];
    const int wv = threadIdx.x >> 6, l = threadIdx.x & 63;
    const int lr = l & 15, kb = l >> 4;
    const int rbase = blockIdx.x * 128 + wv * 32;

    // GEMM1: K=256 over [state_h, aggb], 2 row tiles
    f32x4 acc[2][8] = {};
#pragma unroll
    for (int ks = 0; ks < 8; ++ks) {
        short8 a[2];
#pragma unroll
        for (int rt = 0; rt < 2; ++rt) {
            int row = rbase + rt * 16 + lr;
            int rowc = row < NN ? row : NN - 1;
            const u16* abase = (ks < 4)
                ? (state_h + (size_t)rowc * 128 + ks * 32 + kb * 8)
                : (aggb + (size_t)rowc * 128 + (ks - 4) * 32 + kb * 8);
            a[rt] = *(const short8*)abase;
        }
        const u16* bp = packed + W1OFF + (size_t)(ks * 512 + l) * 8;
#pragma unroll
        for (int nt = 0; nt < 8; ++nt) {
            short8 b = *(const short8*)(bp + nt * 512);
            acc[0][nt] = mfma16(a[0], b, acc[0][nt]);
            acc[1][nt] = mfma16(a[1], b, acc[1][nt]);
        }
    }
    // h = relu(acc + b1) -> stage
#pragma unroll
    for (int nt = 0; nt < 8; ++nt) {
        int col = nt * 16 + lr;
        float b1v = up_b1[col];
#pragma unroll
        for (int rt = 0; rt < 2; ++rt) {
#pragma unroll
            for (int j = 0; j < 4; ++j) {
                int rl = kb * 4 + j;
                float v = acc[rt][nt][j] + b1v;
                v = v > 0.f ? v : 0.f;
                int byte = (rl * 256 + col * 2) ^ ((rl & 7) << 4);
                *(u16*)((char*)stage[wv][rt] + byte) = f2bf(v);
            }
        }
    }
    // GEMM2: delta = h @ W2
    f32x4 acc2[2][8] = {};
#pragma unroll
    for (int ks = 0; ks < 4; ++ks) {
        int byte = (lr * 256 + ks * 64 + kb * 16) ^ ((lr & 7) << 4);
        short8 a[2];
        a[0] = *(const short8*)((char*)stage[wv][0] + byte);
        a[1] = *(const short8*)((char*)stage[wv][1] + byte);
        const u16* bp = packed + W2OFF + (size_t)(ks * 512 + l) * 8;
#pragma unroll
        for (int nt = 0; nt < 8; ++nt) {
            short8 b = *(const short8*)(bp + nt * 512);
            acc2[0][nt] = mfma16(a[0], b, acc2[0][nt]);
            acc2[1][nt] = mfma16(a[1], b, acc2[1][nt]);
        }
    }
    // state_h += delta + b2 (bf16 master); stage <- state_new [wave-local, in-order]
#pragma unroll
    for (int rt = 0; rt < 2; ++rt) {
#pragma unroll
        for (int nt = 0; nt < 8; ++nt) {
            int col = nt * 16 + lr;
            float b2v = up_b2[col];
#pragma unroll
            for (int j = 0; j < 4; ++j) {
                int rl = kb * 4 + j;
                int r = rbase + rt * 16 + rl;
                int rc = r < NN ? r : NN - 1;
                float sold = bf2f((u32)state_h[(size_t)rc * 128 + col]);
                float snew = sold + acc2[rt][nt][j] + b2v;
                u16 hb = f2bf(snew);
                if (r < NN) state_h[(size_t)r * 128 + col] = hb;
                int byte = (rl * 256 + col * 2) ^ ((rl & 7) << 4);
                *(u16*)((char*)stage[wv][rt] + byte) = hb;
            }
        }
    }
    // GEMM3: swb = state_new @ Ws + msg_b
    f32x4 acc3[2][8] = {};
#pragma unroll
    for (int ks = 0; ks < 4; ++ks) {
        int byte = (lr * 256 + ks * 64 + kb * 16) ^ ((lr & 7) << 4);
        short8 a[2];
        a[0] = *(const short8*)((char*)stage[wv][0] + byte);
        a[1] = *(const short8*)((char*)stage[wv][1] + byte);
        const u16* bp = packed + WSOFF + (size_t)(ks * 512 + l) * 8;
#pragma unroll
        for (int nt = 0; nt < 8; ++nt) {
            short8 b = *(const short8*)(bp + nt * 512);
            acc3[0][nt] = mfma16(a[0], b, acc3[0][nt]);
            acc3[1][nt] = mfma16(a[1], b, acc3[1][nt]);
        }
    }
#pragma unroll
    for (int rt = 0; rt < 2; ++rt) {
#pragma unroll
        for (int nt = 0; nt < 8; ++nt) {
            int col = nt * 16 + lr;
            float bias = msg_b[col];
#pragma unroll
            for (int j = 0; j < 4; ++j) {
                int r = rbase + rt * 16 + kb * 4 + j;
                if (r < NN) swb[(size_t)r * 128 + col] = f2bf(acc3[rt][nt][j] + bias);
            }
        }
    }
}

// ---------------- logits: deterministic batched segment mean over sorted batch ----------------

__global__ void k_logits(const u16* __restrict__ state_h, const int* __restrict__ batch,
                         float* __restrict__ out) {
    __shared__ float red[256];
    int b = blockIdx.x, t = threadIdx.x;
    int ch = t & 7, sub = t >> 3;
    int lo = 0, hi = NN;
    while (lo < hi) { int m = (lo + hi) >> 1; if (batch[m] < b) lo = m + 1; else hi = m; }
    int s0 = lo;
    lo = 0; hi = NN;
    while (lo < hi) { int m = (lo + hi) >> 1; if (batch[m] < b + 1) lo = m + 1; else hi = m; }
    int s1 = lo;
    float acc = 0.f;
    for (int n = s0 + sub; n < s1; n += 32)
        acc += bf2f((u32)state_h[(size_t)n * 128 + 120 + ch]);
    red[t] = acc;
    __syncthreads();
    for (int off = 16; off >= 1; off >>= 1) {
        if (sub < off) red[t] += red[t + off * 8];
        __syncthreads();
    }
    if (sub == 0) {
        int c = s1 - s0;
        float cnt = (float)(c > 0 ? c : 1);
        out[b * 8 + ch] = red[ch] / cnt;
    }
}

// ---------------- launch ----------------

extern "C" void kernel_launch(void* const* d_in, const int* in_sizes, int n_in,
                              void* d_out, int out_size, void* d_ws, size_t ws_size,
                              hipStream_t stream) {
    (void)in_sizes; (void)n_in;
    const float* x      = (const float*)d_in[0];
    const int*   eidx   = (const int*)d_in[1];
    const float* eattr  = (const float*)d_in[2];
    const int*   batch  = (const int*)d_in[3];
    const float* enc_w  = (const float*)d_in[4];
    const float* enc_b  = (const float*)d_in[5];
    const float* msg_w  = (const float*)d_in[6];
    const float* msg_b  = (const float*)d_in[7];
    const float* up_w1  = (const float*)d_in[8];
    const float* up_b1  = (const float*)d_in[9];
    const float* up_w2  = (const float*)d_in[10];
    const float* up_b2  = (const float*)d_in[11];
    const int* esrc = eidx;
    const int* edst = eidx + NE;

    char* p = (char*)d_ws;
    size_t off = 0;
    auto carve = [&](size_t bytes) -> char* {
        char* r = p + off;
        off += (bytes + 255) & ~(size_t)255;
        return r;
    };
    u16* state_h   = (u16*)carve((size_t)NN * 128 * 2);
    u16* aggb      = (u16*)carve((size_t)NN * 128 * 2);
    u16* swb       = (u16*)carve((size_t)NN * 128 * 2);
    int* ssrc      = (int*)carve((size_t)NE * 4);
    u16* ea8       = (u16*)carve((size_t)NE * 8 * 2);
    unsigned char* eaw = (unsigned char*)carve((size_t)NE * 128);
    int* rowptr    = (int*)carve((size_t)(NN + 1) * 4);
    int* cursor    = (int*)carve((size_t)NN * 4);
    int* hist      = (int*)carve((size_t)NN * 4);
    int* sexcl     = (int*)carve((size_t)NN * 4);
    int* bsum      = (int*)carve((size_t)256 * 4);
    u16* packed    = (u16*)carve((size_t)PACKN * 2);
    if (off > ws_size) {
        // sentinel: NaN output tells us the workspace was too small
        hipMemsetAsync(d_out, 0xFF, (size_t)out_size * 4, stream);
        return;
    }

    hipMemsetAsync(hist, 0, (size_t)NN * 4, stream);
    k_hist<<<(NE + 255) / 256, 256, 0, stream>>>(edst, hist);
    k_scanA<<<SCAN_B, 256, 0, stream>>>(hist, sexcl, bsum);
    k_scanB<<<1, 256, 0, stream>>>(bsum);
    k_scanC<<<SCAN_B, 256, 0, stream>>>(sexcl, bsum, rowptr, cursor);
    k_scatter<<<(NE + 255) / 256, 256, 0, stream>>>(esrc, edst, eattr, cursor, ssrc, ea8);
    k_eaw<<<EAW_BLOCKS, 256, 0, stream>>>(ea8, msg_w, eaw);
    k_pack<<<(PACKN + 255) / 256, 256, 0, stream>>>(up_w1, up_w2, msg_w, enc_w, packed);
    k_encode<<<(NN + 63) / 64, 256, 0, stream>>>(x, enc_b, msg_b, packed, state_h, swb);
    for (int t = 0; t < T_STEPS; ++t) {
        k_edge<<<(NN + 7) / 8, 256, 0, stream>>>(rowptr, ssrc, eaw, swb, aggb);
        k_update<<<(NN + 127) / 128, 256, 0, stream>>>(up_b1, up_b2, msg_b, packed, aggb,
                                                       state_h, swb);
    }
    k_logits<<<NB, 256, 0, stream>>>(state_h, batch, (float*)d_out);
}

// Round 12
// 1031.345 us; speedup vs baseline: 1.5834x; 1.1009x over previous
//
#include <hip/hip_runtime.h>
#include <hip/hip_bf16.h>

#define NN 50000
#define NE 800000
#define NB 16
#define T_STEPS 12
#define SCAN_B 196  // ceil(NN/256)
#define EAW_BLOCKS 2048

typedef __attribute__((ext_vector_type(8))) short short8;
typedef __attribute__((ext_vector_type(4))) float f32x4;
typedef __attribute__((ext_vector_type(2))) float f32x2;
typedef unsigned short u16;
typedef unsigned int u32;

__device__ __forceinline__ float bf2f(u32 u) {
    union { u32 i; float f; } v; v.i = u << 16; return v.f;
}
__device__ __forceinline__ u16 f2bf(float f) {
    union { float f; u32 i; } v; v.f = f;
    u32 r = v.i + 0x7fffu + ((v.i >> 16) & 1u);
    return (u16)(r >> 16);
}
__device__ __forceinline__ f32x4 mfma16(short8 a, short8 b, f32x4 c) {
    return __builtin_amdgcn_mfma_f32_16x16x32_bf16(a, b, c, 0, 0, 0);
}

// pack 2 floats -> fp8 e4m3 pair in low 16 bits (HW instruction; OCP on gfx950)
__device__ __forceinline__ u32 pk2_fp8(float o0, float o1) {
#if __has_builtin(__builtin_amdgcn_cvt_pk_fp8_f32)
    return (u32)__builtin_amdgcn_cvt_pk_fp8_f32(o0, o1, 0, false);
#else
    u32 a = 0;
    asm("v_cvt_pk_fp8_f32 %0, %1, %2" : "+v"(a) : "v"(o0), "v"(o1));
    return a;
#endif
}
__device__ __forceinline__ u32 pk4_fp8(float o0, float o1, float o2, float o3) {
    return (pk2_fp8(o0, o1) & 0xffffu) | (pk2_fp8(o2, o3) << 16);
}
__device__ __forceinline__ unsigned char f2fp8b(float v) {
    return (unsigned char)(pk2_fp8(v, 0.f) & 0xffu);
}

// decode 4x fp8 e4m3 from u32
__device__ __forceinline__ void fp8x4f(u32 w, float& f0, float& f1, float& f2, float& f3) {
#if __has_builtin(__builtin_amdgcn_cvt_pk_f32_fp8)
    f32x2 r0 = __builtin_amdgcn_cvt_pk_f32_fp8((int)w, false);
    f32x2 r1 = __builtin_amdgcn_cvt_pk_f32_fp8((int)w, true);
    f0 = r0[0]; f1 = r0[1]; f2 = r1[0]; f3 = r1[1];
#else
    f32x2 r0, r1;
    u32 hi = w >> 16;
    asm("v_cvt_pk_f32_fp8 %0, %1" : "=v"(r0) : "v"(w));
    asm("v_cvt_pk_f32_fp8 %0, %1" : "=v"(r1) : "v"(hi));
    f0 = r0[0]; f1 = r0[1]; f2 = r1[0]; f3 = r1[1];
#endif
}

// packed weight layout (bf16): elem(((ks*8+nt)*64+l)*8+j) = W[ks*32+((l>>4))*8+j][nt*16+(l&15)]
#define W1OFF 0
#define W2OFF 32768
#define WSOFF 49152
#define ENCOFF 65536
#define PACKN 73728

// ---------------- setup kernels ----------------

__global__ void k_hist(const int* __restrict__ dst, int* __restrict__ hist) {
    int e = blockIdx.x * 256 + threadIdx.x;
    if (e < NE) atomicAdd(&hist[dst[e]], 1);
}

__global__ void k_scanA(const int* __restrict__ hist, int* __restrict__ excl,
                        int* __restrict__ bsum) {
    __shared__ int sh[256];
    int t = threadIdx.x, b = blockIdx.x;
    int idx = b * 256 + t;
    int v = (idx < NN) ? hist[idx] : 0;
    sh[t] = v;
    __syncthreads();
    for (int off = 1; off < 256; off <<= 1) {
        int add = (t >= off) ? sh[t - off] : 0;
        __syncthreads();
        sh[t] += add;
        __syncthreads();
    }
    if (idx < NN) excl[idx] = sh[t] - v;
    if (t == 255) bsum[b] = sh[255];
}

__global__ void k_scanB(int* __restrict__ bsum) {
    __shared__ int sh[256];
    int t = threadIdx.x;
    int v = (t < SCAN_B) ? bsum[t] : 0;
    sh[t] = v;
    __syncthreads();
    for (int off = 1; off < 256; off <<= 1) {
        int add = (t >= off) ? sh[t - off] : 0;
        __syncthreads();
        sh[t] += add;
        __syncthreads();
    }
    if (t < SCAN_B) bsum[t] = sh[t] - v;  // exclusive
}

__global__ void k_scanC(const int* __restrict__ excl, const int* __restrict__ bsum,
                        int* __restrict__ rowptr, int* __restrict__ cursor) {
    int idx = blockIdx.x * 256 + threadIdx.x;
    if (idx < NN) {
        int r = excl[idx] + bsum[blockIdx.x];
        rowptr[idx] = r;
        cursor[idx] = r;
    }
    if (idx == 0) rowptr[NN] = NE;
}

// scatter (src id + bf16 edge-attr) into CSR order; atomic-latency-bound, stores ~free.
__global__ void k_scatter(const int* __restrict__ src, const int* __restrict__ dst,
                          const float* __restrict__ eattr, int* __restrict__ cursor,
                          int* __restrict__ ssrc, u16* __restrict__ ea8) {
    int e = blockIdx.x * 256 + threadIdx.x;
    if (e >= NE) return;
    int d = dst[e];
    int pos = atomicAdd(&cursor[d], 1);
    ssrc[pos] = src[e];
    const float* ap = eattr + (size_t)e * 8;
    uint4 w;
    w.x = (u32)f2bf(ap[0]) | ((u32)f2bf(ap[1]) << 16);
    w.y = (u32)f2bf(ap[2]) | ((u32)f2bf(ap[3]) << 16);
    w.z = (u32)f2bf(ap[4]) | ((u32)f2bf(ap[5]) << 16);
    w.w = (u32)f2bf(ap[6]) | ((u32)f2bf(ap[7]) << 16);
    *(uint4*)(ea8 + (size_t)pos * 8) = w;
}

// eaw[p][c] = fp8( sum_k ea8[p][k] * msg_w[128+k][c] ) — fully coalesced stream.
__global__ __launch_bounds__(256) void k_eaw(
    const u16* __restrict__ ea8, const float* __restrict__ msg_w,
    unsigned char* __restrict__ eaw) {
    const int tid = threadIdx.x;
    const int hex = tid & 15;   // channel slice [hex*8, hex*8+8)
    const int esub = tid >> 4;  // 0..15
    float w[8][8];
#pragma unroll
    for (int k = 0; k < 8; ++k) {
        float4 v0 = *(const float4*)(msg_w + (size_t)(128 + k) * 128 + hex * 8);
        float4 v1 = *(const float4*)(msg_w + (size_t)(128 + k) * 128 + hex * 8 + 4);
        w[k][0] = v0.x; w[k][1] = v0.y; w[k][2] = v0.z; w[k][3] = v0.w;
        w[k][4] = v1.x; w[k][5] = v1.y; w[k][6] = v1.z; w[k][7] = v1.w;
    }
    int p = blockIdx.x * 16 + esub;
    if (p >= NE) return;
    uint4 ev = *(const uint4*)(ea8 + (size_t)p * 8);
    while (true) {
        int pn = p + EAW_BLOCKS * 16;
        bool more = pn < NE;
        uint4 evn;
        if (more) evn = *(const uint4*)(ea8 + (size_t)pn * 8);
        float ef[8];
        ef[0] = bf2f(ev.x & 0xffffu); ef[1] = bf2f(ev.x >> 16);
        ef[2] = bf2f(ev.y & 0xffffu); ef[3] = bf2f(ev.y >> 16);
        ef[4] = bf2f(ev.z & 0xffffu); ef[5] = bf2f(ev.z >> 16);
        ef[6] = bf2f(ev.w & 0xffffu); ef[7] = bf2f(ev.w >> 16);
        float o[8];
#pragma unroll
        for (int c = 0; c < 8; ++c) o[c] = ef[0] * w[0][c];
#pragma unroll
        for (int k = 1; k < 8; ++k)
#pragma unroll
            for (int c = 0; c < 8; ++c) o[c] += ef[k] * w[k][c];
        uint2 q;
        q.x = pk4_fp8(o[0], o[1], o[2], o[3]);
        q.y = pk4_fp8(o[4], o[5], o[6], o[7]);
        *(uint2*)(eaw + (size_t)p * 128 + hex * 8) = q;
        if (!more) break;
        p = pn;
        ev = evn;
    }
}

__global__ void k_pack(const float* __restrict__ up_w1, const float* __restrict__ up_w2,
                       const float* __restrict__ msg_w, const float* __restrict__ enc_w,
                       u16* __restrict__ packed) {
    int idx = blockIdx.x * 256 + threadIdx.x;
    if (idx >= PACKN) return;
    const float* srcp; int local;
    if (idx < W2OFF)        { srcp = up_w1; local = idx; }
    else if (idx < WSOFF)   { srcp = up_w2; local = idx - W2OFF; }
    else if (idx < ENCOFF)  { srcp = msg_w; local = idx - WSOFF; }   // rows 0..127 (state part)
    else                    { srcp = enc_w; local = idx - ENCOFF; }
    int j = local & 7;
    int l = (local >> 3) & 63;
    int ntks = local >> 9;
    int nt = ntks & 7;
    int ks = ntks >> 3;
    int krow = ks * 32 + (l >> 4) * 8 + j;
    int col = nt * 16 + (l & 15);
    packed[idx] = f2bf(srcp[krow * 128 + col]);
}

// ---------------- encoder: state_h = bf16(relu(x@enc_w+enc_b)); swf8 = fp8(state@Ws+msg_b) ----------------

__global__ __launch_bounds__(256) void k_encode(
    const float* __restrict__ x, const float* __restrict__ enc_b,
    const float* __restrict__ msg_b, const u16* __restrict__ packed,
    u16* __restrict__ state_h, unsigned char* __restrict__ swf8) {
    __shared__ u16 stage[4][2048];
    const int wv = threadIdx.x >> 6, l = threadIdx.x & 63;
    const int lr = l & 15, kb = l >> 4;
    const int rb = blockIdx.x * 64 + wv * 16;
    const int row = rb + lr;
    const int rowc = row < NN ? row : NN - 1;

    f32x4 acc[8] = {};
#pragma unroll
    for (int ks = 0; ks < 2; ++ks) {
        const float* ap = x + (size_t)rowc * 64 + ks * 32 + kb * 8;
        float4 a0 = *(const float4*)ap;
        float4 a1 = *(const float4*)(ap + 4);
        short8 a;
        a[0] = (short)f2bf(a0.x); a[1] = (short)f2bf(a0.y);
        a[2] = (short)f2bf(a0.z); a[3] = (short)f2bf(a0.w);
        a[4] = (short)f2bf(a1.x); a[5] = (short)f2bf(a1.y);
        a[6] = (short)f2bf(a1.z); a[7] = (short)f2bf(a1.w);
        const u16* bp = packed + ENCOFF + (size_t)(ks * 512 + l) * 8;
#pragma unroll
        for (int nt = 0; nt < 8; ++nt) {
            short8 b = *(const short8*)(bp + nt * 512);
            acc[nt] = mfma16(a, b, acc[nt]);
        }
    }
#pragma unroll
    for (int nt = 0; nt < 8; ++nt) {
        int col = nt * 16 + lr;
        float bias = enc_b[col];
#pragma unroll
        for (int j = 0; j < 4; ++j) {
            int rl = kb * 4 + j;
            int r = rb + rl;
            float v = acc[nt][j] + bias;
            v = v > 0.f ? v : 0.f;
            u16 h = f2bf(v);
            if (r < NN) state_h[(size_t)r * 128 + col] = h;
            int byte = (rl * 256 + col * 2) ^ ((rl & 7) << 4);
            *(u16*)((char*)stage[wv] + byte) = h;
        }
    }
    f32x4 acc3[8] = {};
#pragma unroll
    for (int ks = 0; ks < 4; ++ks) {
        int byte = (lr * 256 + ks * 64 + kb * 16) ^ ((lr & 7) << 4);
        short8 a = *(const short8*)((char*)stage[wv] + byte);
        const u16* bp = packed + WSOFF + (size_t)(ks * 512 + l) * 8;
#pragma unroll
        for (int nt = 0; nt < 8; ++nt) {
            short8 b = *(const short8*)(bp + nt * 512);
            acc3[nt] = mfma16(a, b, acc3[nt]);
        }
    }
#pragma unroll
    for (int nt = 0; nt < 8; ++nt) {
        int col = nt * 16 + lr;
        float bias = msg_b[col];
#pragma unroll
        for (int j = 0; j < 4; ++j) {
            int r = rb + kb * 4 + j;
            if (r < NN) swf8[(size_t)r * 128 + col] = f2fp8b(acc3[nt][j] + bias);
        }
    }
}

// ---------------- edge kernel: agg[n] = mean_e relu(SW[src_e] + EAW[e]) ----------------
// 2 nodes/wave x 4 edge-slots x 8 lanes (16 ch/lane); eaw AND swb both fp8 (16B/lane each).
// Software pipeline: ssrc prefetched 2 iters ahead, eaw+swb DATA 1 iter ahead.

__global__ __launch_bounds__(256) void k_edge(
    const int* __restrict__ rowptr, const int* __restrict__ ssrc,
    const unsigned char* __restrict__ eaw, const unsigned char* __restrict__ swf8,
    u16* __restrict__ aggb) {
    __shared__ float red[4][2][4][129];  // [wave][node][slot][ch padded]
    const int wv = threadIdx.x >> 6, l = threadIdx.x & 63;
    const int half = l >> 5;          // node within wave
    const int slot = (l >> 3) & 3;    // edge slot
    const int g = l & 7;              // 16-ch group
    const int n = blockIdx.x * 8 + wv * 2 + half;
    if (n >= NN) return;
    const int e0 = rowptr[n], e1 = rowptr[n + 1];
    float acc[16];
#pragma unroll
    for (int c = 0; c < 16; ++c) acc[c] = 0.f;

    int i = e0 + slot;
    uint4 qc = {0, 0, 0, 0}, sac = {0, 0, 0, 0};
    if (i < e1) {
        int sc = ssrc[i];
        qc = *(const uint4*)(eaw + (size_t)i * 128 + g * 16);
        sac = *(const uint4*)(swf8 + (size_t)sc * 128 + g * 16);
    }
    int inext = i + 4;
    int snext = (inext < e1) ? ssrc[inext] : 0;
    while (i < e1) {
        // prefetch iteration i+4 (data) and i+8 (index)
        int i2 = inext + 4;
        int s2 = (i2 < e1) ? ssrc[i2] : 0;
        uint4 qn = {0, 0, 0, 0}, san = {0, 0, 0, 0};
        if (inext < e1) {
            qn = *(const uint4*)(eaw + (size_t)inext * 128 + g * 16);
            san = *(const uint4*)(swf8 + (size_t)snext * 128 + g * 16);
        }
        // compute on current staged data
        float ef[16], sw[16];
        fp8x4f(qc.x, ef[0], ef[1], ef[2], ef[3]);
        fp8x4f(qc.y, ef[4], ef[5], ef[6], ef[7]);
        fp8x4f(qc.z, ef[8], ef[9], ef[10], ef[11]);
        fp8x4f(qc.w, ef[12], ef[13], ef[14], ef[15]);
        fp8x4f(sac.x, sw[0], sw[1], sw[2], sw[3]);
        fp8x4f(sac.y, sw[4], sw[5], sw[6], sw[7]);
        fp8x4f(sac.z, sw[8], sw[9], sw[10], sw[11]);
        fp8x4f(sac.w, sw[12], sw[13], sw[14], sw[15]);
#pragma unroll
        for (int c = 0; c < 16; ++c) {
            float m = sw[c] + ef[c];
            acc[c] += m > 0.f ? m : 0.f;
        }
        qc = qn; sac = san;
        i = inext;
        inext = i2;
        snext = s2;
    }
    // per-slot partials -> LDS (wave-local, in-order per wave; no barrier)
    float* rp = &red[wv][half][slot][g * 16];
#pragma unroll
    for (int c = 0; c < 16; c += 4) {
        f32x4 v = {acc[c], acc[c + 1], acc[c + 2], acc[c + 3]};
        *(f32x4*)(rp + c) = v;
    }
    // reduce 4 slots; lane lo handles 4 channels
    const int lo = l & 31;
    const int ch = lo * 4;
    f32x4 sum = *(const f32x4*)&red[wv][half][0][ch];
#pragma unroll
    for (int sl = 1; sl < 4; ++sl) {
        f32x4 v = *(const f32x4*)&red[wv][half][sl][ch];
        sum[0] += v[0]; sum[1] += v[1]; sum[2] += v[2]; sum[3] += v[3];
    }
    int dg = e1 - e0;
    float inv = 1.f / (float)(dg > 0 ? dg : 1);
    uint2 outw;
    outw.x = (u32)f2bf(sum[0] * inv) | ((u32)f2bf(sum[1] * inv) << 16);
    outw.y = (u32)f2bf(sum[2] * inv) | ((u32)f2bf(sum[3] * inv) << 16);
    *(uint2*)(aggb + (size_t)n * 128 + ch) = outw;
}

// ---------------- update kernel (R=2 row tiles/wave, bf16 state master, fp8 swb out): ----------------
// h=relu([state,agg]@W1+b1); state+=h@W2+b2; swf8=fp8(state@Ws+msg_b)

__global__ __launch_bounds__(256) void k_update(
    const float* __restrict__ up_b1, const float* __restrict__ up_b2,
    const float* __restrict__ msg_b, const u16* __restrict__ packed,
    const u16* __restrict__ aggb, u16* __restrict__ state_h,
    unsigned char* __restrict__ swf8) {
    __shared__ u16 stage[4][2][2048];
    const int wv = threadIdx.x >> 6, l = threadIdx.x & 63;
    const int lr = l & 15, kb = l >> 4;
    const int rbase = blockIdx.x * 128 + wv * 32;

    // GEMM1: K=256 over [state_h, aggb], 2 row tiles
    f32x4 acc[2][8] = {};
#pragma unroll
    for (int ks = 0; ks < 8; ++ks) {
        short8 a[2];
#pragma unroll
        for (int rt = 0; rt < 2; ++rt) {
            int row = rbase + rt * 16 + lr;
            int rowc = row < NN ? row : NN - 1;
            const u16* abase = (ks < 4)
                ? (state_h + (size_t)rowc * 128 + ks * 32 + kb * 8)
                : (aggb + (size_t)rowc * 128 + (ks - 4) * 32 + kb * 8);
            a[rt] = *(const short8*)abase;
        }
        const u16* bp = packed + W1OFF + (size_t)(ks * 512 + l) * 8;
#pragma unroll
        for (int nt = 0; nt < 8; ++nt) {
            short8 b = *(const short8*)(bp + nt * 512);
            acc[0][nt] = mfma16(a[0], b, acc[0][nt]);
            acc[1][nt] = mfma16(a[1], b, acc[1][nt]);
        }
    }
    // h = relu(acc + b1) -> stage
#pragma unroll
    for (int nt = 0; nt < 8; ++nt) {
        int col = nt * 16 + lr;
        float b1v = up_b1[col];
#pragma unroll
        for (int rt = 0; rt < 2; ++rt) {
#pragma unroll
            for (int j = 0; j < 4; ++j) {
                int rl = kb * 4 + j;
                float v = acc[rt][nt][j] + b1v;
                v = v > 0.f ? v : 0.f;
                int byte = (rl * 256 + col * 2) ^ ((rl & 7) << 4);
                *(u16*)((char*)stage[wv][rt] + byte) = f2bf(v);
            }
        }
    }
    // GEMM2: delta = h @ W2
    f32x4 acc2[2][8] = {};
#pragma unroll
    for (int ks = 0; ks < 4; ++ks) {
        int byte = (lr * 256 + ks * 64 + kb * 16) ^ ((lr & 7) << 4);
        short8 a[2];
        a[0] = *(const short8*)((char*)stage[wv][0] + byte);
        a[1] = *(const short8*)((char*)stage[wv][1] + byte);
        const u16* bp = packed + W2OFF + (size_t)(ks * 512 + l) * 8;
#pragma unroll
        for (int nt = 0; nt < 8; ++nt) {
            short8 b = *(const short8*)(bp + nt * 512);
            acc2[0][nt] = mfma16(a[0], b, acc2[0][nt]);
            acc2[1][nt] = mfma16(a[1], b, acc2[1][nt]);
        }
    }
    // state_h += delta + b2 (bf16 master); stage <- state_new [wave-local, in-order]
#pragma unroll
    for (int rt = 0; rt < 2; ++rt) {
#pragma unroll
        for (int nt = 0; nt < 8; ++nt) {
            int col = nt * 16 + lr;
            float b2v = up_b2[col];
#pragma unroll
            for (int j = 0; j < 4; ++j) {
                int rl = kb * 4 + j;
                int r = rbase + rt * 16 + rl;
                int rc = r < NN ? r : NN - 1;
                float sold = bf2f((u32)state_h[(size_t)rc * 128 + col]);
                float snew = sold + acc2[rt][nt][j] + b2v;
                u16 hb = f2bf(snew);
                if (r < NN) state_h[(size_t)r * 128 + col] = hb;
                int byte = (rl * 256 + col * 2) ^ ((rl & 7) << 4);
                *(u16*)((char*)stage[wv][rt] + byte) = hb;
            }
        }
    }
    // GEMM3: swf8 = fp8(state_new @ Ws + msg_b)
    f32x4 acc3[2][8] = {};
#pragma unroll
    for (int ks = 0; ks < 4; ++ks) {
        int byte = (lr * 256 + ks * 64 + kb * 16) ^ ((lr & 7) << 4);
        short8 a[2];
        a[0] = *(const short8*)((char*)stage[wv][0] + byte);
        a[1] = *(const short8*)((char*)stage[wv][1] + byte);
        const u16* bp = packed + WSOFF + (size_t)(ks * 512 + l) * 8;
#pragma unroll
        for (int nt = 0; nt < 8; ++nt) {
            short8 b = *(const short8*)(bp + nt * 512);
            acc3[0][nt] = mfma16(a[0], b, acc3[0][nt]);
            acc3[1][nt] = mfma16(a[1], b, acc3[1][nt]);
        }
    }
#pragma unroll
    for (int rt = 0; rt < 2; ++rt) {
#pragma unroll
        for (int nt = 0; nt < 8; ++nt) {
            int col = nt * 16 + lr;
            float bias = msg_b[col];
#pragma unroll
            for (int j = 0; j < 4; ++j) {
                int r = rbase + rt * 16 + kb * 4 + j;
                if (r < NN) swf8[(size_t)r * 128 + col] = f2fp8b(acc3[rt][nt][j] + bias);
            }
        }
    }
}

// ---------------- logits: deterministic batched segment mean over sorted batch ----------------

__global__ void k_logits(const u16* __restrict__ state_h, const int* __restrict__ batch,
                         float* __restrict__ out) {
    __shared__ float red[256];
    int b = blockIdx.x, t = threadIdx.x;
    int ch = t & 7, sub = t >> 3;
    int lo = 0, hi = NN;
    while (lo < hi) { int m = (lo + hi) >> 1; if (batch[m] < b) lo = m + 1; else hi = m; }
    int s0 = lo;
    lo = 0; hi = NN;
    while (lo < hi) { int m = (lo + hi) >> 1; if (batch[m] < b + 1) lo = m + 1; else hi = m; }
    int s1 = lo;
    float acc = 0.f;
    for (int n = s0 + sub; n < s1; n += 32)
        acc += bf2f((u32)state_h[(size_t)n * 128 + 120 + ch]);
    red[t] = acc;
    __syncthreads();
    for (int off = 16; off >= 1; off >>= 1) {
        if (sub < off) red[t] += red[t + off * 8];
        __syncthreads();
    }
    if (sub == 0) {
        int c = s1 - s0;
        float cnt = (float)(c > 0 ? c : 1);
        out[b * 8 + ch] = red[ch] / cnt;
    }
}

// ---------------- launch ----------------

extern "C" void kernel_launch(void* const* d_in, const int* in_sizes, int n_in,
                              void* d_out, int out_size, void* d_ws, size_t ws_size,
                              hipStream_t stream) {
    (void)in_sizes; (void)n_in;
    const float* x      = (const float*)d_in[0];
    const int*   eidx   = (const int*)d_in[1];
    const float* eattr  = (const float*)d_in[2];
    const int*   batch  = (const int*)d_in[3];
    const float* enc_w  = (const float*)d_in[4];
    const float* enc_b  = (const float*)d_in[5];
    const float* msg_w  = (const float*)d_in[6];
    const float* msg_b  = (const float*)d_in[7];
    const float* up_w1  = (const float*)d_in[8];
    const float* up_b1  = (const float*)d_in[9];
    const float* up_w2  = (const float*)d_in[10];
    const float* up_b2  = (const float*)d_in[11];
    const int* esrc = eidx;
    const int* edst = eidx + NE;

    char* p = (char*)d_ws;
    size_t off = 0;
    auto carve = [&](size_t bytes) -> char* {
        char* r = p + off;
        off += (bytes + 255) & ~(size_t)255;
        return r;
    };
    u16* state_h   = (u16*)carve((size_t)NN * 128 * 2);
    u16* aggb      = (u16*)carve((size_t)NN * 128 * 2);
    unsigned char* swf8 = (unsigned char*)carve((size_t)NN * 128);
    int* ssrc      = (int*)carve((size_t)NE * 4);
    u16* ea8       = (u16*)carve((size_t)NE * 8 * 2);
    unsigned char* eaw = (unsigned char*)carve((size_t)NE * 128);
    int* rowptr    = (int*)carve((size_t)(NN + 1) * 4);
    int* cursor    = (int*)carve((size_t)NN * 4);
    int* hist      = (int*)carve((size_t)NN * 4);
    int* sexcl     = (int*)carve((size_t)NN * 4);
    int* bsum      = (int*)carve((size_t)256 * 4);
    u16* packed    = (u16*)carve((size_t)PACKN * 2);
    if (off > ws_size) {
        // sentinel: NaN output tells us the workspace was too small
        hipMemsetAsync(d_out, 0xFF, (size_t)out_size * 4, stream);
        return;
    }

    hipMemsetAsync(hist, 0, (size_t)NN * 4, stream);
    k_hist<<<(NE + 255) / 256, 256, 0, stream>>>(edst, hist);
    k_scanA<<<SCAN_B, 256, 0, stream>>>(hist, sexcl, bsum);
    k_scanB<<<1, 256, 0, stream>>>(bsum);
    k_scanC<<<SCAN_B, 256, 0, stream>>>(sexcl, bsum, rowptr, cursor);
    k_scatter<<<(NE + 255) / 256, 256, 0, stream>>>(esrc, edst, eattr, cursor, ssrc, ea8);
    k_eaw<<<EAW_BLOCKS, 256, 0, stream>>>(ea8, msg_w, eaw);
    k_pack<<<(PACKN + 255) / 256, 256, 0, stream>>>(up_w1, up_w2, msg_w, enc_w, packed);
    k_encode<<<(NN + 63) / 64, 256, 0, stream>>>(x, enc_b, msg_b, packed, state_h, swf8);
    for (int t = 0; t < T_STEPS; ++t) {
        k_edge<<<(NN + 7) / 8, 256, 0, stream>>>(rowptr, ssrc, eaw, swf8, aggb);
        k_update<<<(NN + 127) / 128, 256, 0, stream>>>(up_b1, up_b2, msg_b, packed, aggb,
                                                       state_h, swf8);
    }
    k_logits<<<NB, 256, 0, stream>>>(state_h, batch, (float*)d_out);
}